// Round 13
// baseline (463.305 us; speedup 1.0000x reference)
//
#include <hip/hip_runtime.h>

#define DIM 384
#define NH 12
#define NT 54   // 49 window + 5 prompt tokens
#define NWIN 64
#define MTOT 110592             // 2048 * 54
#define HS ((size_t)MTOT * 32)  // per-head plane in h-major Q/K/V

typedef __attribute__((ext_vector_type(8))) short short8;
typedef __attribute__((ext_vector_type(4))) float f32x4;

__device__ __forceinline__ unsigned short f2bf(float f) {
  unsigned int u = __float_as_uint(f);
  u += 0x7fffu + ((u >> 16) & 1u);   // round-to-nearest-even
  return (unsigned short)(u >> 16);
}
__device__ __forceinline__ float bf2f(unsigned short s) {
  return __uint_as_float((unsigned int)s << 16);
}
// packed f32->bf16 (RTNE, same result as f2bf): D.lo=bf16(a), D.hi=bf16(b)
__device__ __forceinline__ unsigned int cvtpk(float a, float b) {
  unsigned int r;
  asm("v_cvt_pk_bf16_f32 %0, %1, %2" : "=v"(r) : "v"(a), "v"(b));
  return r;
}
// async global->LDS, 16B per lane; LDS dest = wave-uniform base + lane*16
__device__ __forceinline__ void gload16(const unsigned short* g,
                                        unsigned short* l) {
  __builtin_amdgcn_global_load_lds(
      (const __attribute__((address_space(1))) void*)g,
      (__attribute__((address_space(3))) void*)l, 16, 0, 0);
}

// ===================================================== FAST PATH ==========
// prep2: weights -> bf16; combined bias+mask table bmt in TRANSPOSED layout
// bmt[w][h][col][row] bf16: -1e30 in pad rows/cols, bias+mask elsewhere
__global__ __launch_bounds__(256) void prep2_kernel(
    const float* __restrict__ qkv_w, const float* __restrict__ proj_w,
    const float* __restrict__ mask, const float* __restrict__ rpb,
    const int* __restrict__ rel,
    unsigned short* __restrict__ Wq, unsigned short* __restrict__ Wp,
    unsigned short* __restrict__ bmt) {
  int idx = blockIdx.x * 256 + threadIdx.x;
  if (idx < 1152 * 384) { Wq[idx] = f2bf(qkv_w[idx]); return; }
  idx -= 1152 * 384;
  if (idx < 384 * 384) { Wp[idx] = f2bf(proj_w[idx]); return; }
  idx -= 384 * 384;
  if (idx < NWIN * NH * 64 * 64) {
    int w = idx / (NH * 4096);
    int rem = idx - w * (NH * 4096);
    int h = rem >> 12, r = (rem >> 6) & 63, c = rem & 63;
    float v;
    if (r >= NT || c >= NT) v = -1e30f;
    else if (r >= 5 && c >= 5)
      v = rpb[rel[(r - 5) * 49 + (c - 5)] * NH + h] +
          mask[w * 2401 + (r - 5) * 49 + (c - 5)];
    else v = 0.0f;
    // transposed store: [w][h][c][r]
    bmt[w * (NH * 4096) + (h << 12) + (c << 6) + r] = f2bf(v);
  }
}

// QKV GEMM v7: A = fp32 x, converted in staging (cvtpk, RTNE — bit-identical
// to convert_x+gemm5 path) into padded LDS; B = Wq bf16 via global_load_lds
// w16 into unpadded XOR-swizzled tile. Simple 2-barrier loop.
// grid = 7776 = 8 xcd * 108 m * 9 n.  C[m][n] = x[m][k]*Wq[n][k]+b[n]
__global__ __launch_bounds__(256) void qkv_gemm6(
    const float* __restrict__ x, const unsigned short* __restrict__ Wq,
    const float* __restrict__ qkv_b,
    unsigned short* __restrict__ Qb, unsigned short* __restrict__ Kb,
    unsigned short* __restrict__ Vb) {
  __shared__ unsigned short As[128][72];   // padded, reg-staged
  __shared__ unsigned short Bs[128][64];   // unpadded, gload_lds + swizzle
  const int s = blockIdx.x;
  const int xcd = s & 7, slot = s >> 3;
  const size_t m0 = (size_t)(xcd * 108 + slot / 9) * 128;
  const int n0 = (slot % 9) * 128;
  const int tid = threadIdx.x;
  const int wv = tid >> 6, ln = tid & 63, g = ln >> 4, lc = ln & 15;
  const int wr = (wv >> 1) * 64, wc = (wv & 1) * 64;
  const int l7 = lc & 7;
  const int srow = tid >> 3, l8 = tid & 7;       // A staging map
  const int lr8 = ln >> 3;                       // B staging row-in-8
  const int sc8 = (((ln & 7) ^ lr8) & 7) * 8;    // B swizzled source chunk

  f32x4 acc[4][4];
#pragma unroll
  for (int i = 0; i < 4; ++i)
#pragma unroll
    for (int j = 0; j < 4; ++j) acc[i][j] = (f32x4){0.f, 0.f, 0.f, 0.f};

#pragma unroll
  for (int kc = 0; kc < 6; ++kc) {
    const int k0 = kc * 64;
    if (kc) __syncthreads();          // all waves done reading prev tile
    // ---- B: async gload (swizzled source, linear dest) ----
#pragma unroll
    for (int it = 0; it < 4; ++it) {
      const int r0 = wv * 32 + it * 8;
      gload16(&Wq[(size_t)(n0 + r0 + lr8) * 384 + k0 + sc8], &Bs[r0][0]);
    }
    // ---- A: fp32 load -> cvtpk -> LDS (fused conversion) ----
#pragma unroll
    for (int it = 0; it < 4; ++it) {
      const int r = srow + it * 32;
      const float* ap = &x[(m0 + r) * 384 + k0 + l8 * 8];
      float4 fa = *(const float4*)ap;
      float4 fb = *(const float4*)(ap + 4);
      uint4 u;
      u.x = cvtpk(fa.x, fa.y);
      u.y = cvtpk(fa.z, fa.w);
      u.z = cvtpk(fb.x, fb.y);
      u.w = cvtpk(fb.z, fb.w);
      *(uint4*)&As[r][l8 * 8] = u;
    }
    __syncthreads();                  // drains vm+lgkm -> tiles visible
#pragma unroll
    for (int kk = 0; kk < 2; ++kk) {
      const int cix = (((kk * 4 + g) ^ l7)) * 8;   // B swizzled read chunk
      short8 af[4], bfv[4];
#pragma unroll
      for (int ms = 0; ms < 4; ++ms)
        af[ms] = *(const short8*)&As[wr + ms * 16 + lc][kk * 32 + g * 8];
#pragma unroll
      for (int ns = 0; ns < 4; ++ns)
        bfv[ns] = *(const short8*)&Bs[wc + ns * 16 + lc][cix];
#pragma unroll
      for (int ms = 0; ms < 4; ++ms)
#pragma unroll
        for (int ns = 0; ns < 4; ++ns)
          acc[ms][ns] = __builtin_amdgcn_mfma_f32_16x16x32_bf16(
              af[ms], bfv[ns], acc[ms][ns], 0, 0, 0);
    }
  }

  const int sel = n0 / 384;                       // 384 = 3*128, no crossing
  const float factor = (sel == 0) ? 0.17677669529663687f : 1.0f;
  unsigned short* outp = (sel == 0) ? Qb : (sel == 1 ? Kb : Vb);
#pragma unroll
  for (int ns = 0; ns < 4; ++ns) {
    const int n = n0 + wc + ns * 16 + lc;
    const int rl = n - sel * 384;
    const int h = rl >> 5, d = rl & 31;           // 16-chunk stays in one head
    const float bias = qkv_b[n];
#pragma unroll
    for (int ms = 0; ms < 4; ++ms) {
      const size_t mrow = m0 + wr + ms * 16 + g * 4;
      const float v0 = (acc[ms][ns][0] + bias) * factor;
      const float v1 = (acc[ms][ns][1] + bias) * factor;
      const float v2 = (acc[ms][ns][2] + bias) * factor;
      const float v3 = (acc[ms][ns][3] + bias) * factor;
      const unsigned int u01 = cvtpk(v0, v1);
      const unsigned int u23 = cvtpk(v2, v3);
      unsigned short* p = &outp[(size_t)h * HS + mrow * 32 + d];
      p[0]  = (unsigned short)(u01 & 0xffffu);
      p[32] = (unsigned short)(u01 >> 16);
      p[64] = (unsigned short)(u23 & 0xffffu);
      p[96] = (unsigned short)(u23 >> 16);
    }
  }
}

// attention (R11-proven attn2, byte-identical): w-locality XCD mapping;
// hoisted K/bias loads; shuffle softmax.
// grid = 24576 = 8 xcd * (8 wl * 32 batch * 12 h)
__global__ __launch_bounds__(256) void attn2_kernel(
    unsigned short* __restrict__ Qb, const unsigned short* __restrict__ Kb,
    const unsigned short* __restrict__ Vb, const unsigned short* __restrict__ bmt) {
  __shared__ unsigned short Ps[NT][72];
  __shared__ unsigned short vT[32][72];
  const int s = blockIdx.x;
  const int xcd = s & 7, r3 = s >> 3;       // r3 in [0,3072)
  const int h = r3 % 12;
  const int t2 = r3 / 12;                    // [0,256)
  const int batch = t2 & 31;
  const int w = xcd * 8 + (t2 >> 5);         // this XCD's 8 windows
  const int b = batch * 64 + w;
  const int tid = threadIdx.x;
  const int wv = tid >> 6, ln = tid & 63, g = ln >> 4, lc = ln & 15;
  const int m0 = wv * 16;
  const size_t base = (size_t)b * NT;
  const int arow = (m0 + lc < NT) ? (m0 + lc) : (NT - 1);
  unsigned short* Qh = Qb + (size_t)h * HS;
  const unsigned short* Kh = Kb + (size_t)h * HS;
  const unsigned short* Vh = Vb + (size_t)h * HS;

  // zero vT pad cols m=54..63 (P=0 there; keep product finite); 320 > 256
  for (int i = tid; i < 320; i += 256) {
    int d = i / 10, m = NT + (i - d * 10);
    vT[d][m] = 0;
  }

  // ---- issue ALL global loads up front (10 independent loads in flight) ----
  const int vr = tid >> 2, vc = (tid & 3) * 8;
  short8 vv;
  if (tid < 216)
    vv = *(const short8*)&Vh[(base + vr) * 32 + vc];

  short8 a = *(const short8*)&Qh[(base + arow) * 32 + g * 8];
  const unsigned short* bmh = &bmt[(size_t)(w * NH + h) << 12];  // [c][r]
  const int row0 = m0 + g * 4;
  short8 kb[4];
  uint2 uu[4];
#pragma unroll
  for (int t = 0; t < 4; ++t) {
    const int col = t * 16 + lc;
    const int kr = (col < NT) ? col : (NT - 1);
    kb[t] = *(const short8*)&Kh[(base + kr) * 32 + g * 8];
    uu[t] = *(const uint2*)&bmh[(col << 6) + row0];  // 4 bf16 rows r0..r0+3
  }

  // ---- S = q@k^T with C initialized from transposed bias+mask table ----
  f32x4 sac[4];
#pragma unroll
  for (int t = 0; t < 4; ++t) {
    f32x4 c0;
    c0[0] = bf2f((unsigned short)(uu[t].x & 0xffffu));
    c0[1] = bf2f((unsigned short)(uu[t].x >> 16));
    c0[2] = bf2f((unsigned short)(uu[t].y & 0xffffu));
    c0[3] = bf2f((unsigned short)(uu[t].y >> 16));
    sac[t] = __builtin_amdgcn_mfma_f32_16x16x32_bf16(a, kb[t], c0, 0, 0, 0);
  }
  // ---- row softmax (16-lane groups own rows) ----
  float rmax[4] = {-3.0e38f, -3.0e38f, -3.0e38f, -3.0e38f};
#pragma unroll
  for (int t = 0; t < 4; ++t)
#pragma unroll
    for (int rr = 0; rr < 4; ++rr) rmax[rr] = fmaxf(rmax[rr], sac[t][rr]);
#pragma unroll
  for (int rr = 0; rr < 4; ++rr)
#pragma unroll
    for (int off = 1; off < 16; off <<= 1)
      rmax[rr] = fmaxf(rmax[rr], __shfl_xor(rmax[rr], off));
  float rsum[4] = {0.f, 0.f, 0.f, 0.f};
#pragma unroll
  for (int t = 0; t < 4; ++t)
#pragma unroll
    for (int rr = 0; rr < 4; ++rr) {
      float p = __expf(sac[t][rr] - rmax[rr]);
      sac[t][rr] = p;
      rsum[rr] += p;
    }
#pragma unroll
  for (int rr = 0; rr < 4; ++rr) {
#pragma unroll
    for (int off = 1; off < 16; off <<= 1)
      rsum[rr] += __shfl_xor(rsum[rr], off);
    rsum[rr] = 1.0f / rsum[rr];
  }
#pragma unroll
  for (int t = 0; t < 4; ++t) {
    const int col = t * 16 + lc;
    const unsigned int u01 = cvtpk(sac[t][0] * rsum[0], sac[t][1] * rsum[1]);
    const unsigned int u23 = cvtpk(sac[t][2] * rsum[2], sac[t][3] * rsum[3]);
    if (row0 < NT)     Ps[row0][col]     = (unsigned short)(u01 & 0xffffu);
    if (row0 + 1 < NT) Ps[row0 + 1][col] = (unsigned short)(u01 >> 16);
    if (row0 + 2 < NT) Ps[row0 + 2][col] = (unsigned short)(u23 & 0xffffu);
    if (row0 + 3 < NT) Ps[row0 + 3][col] = (unsigned short)(u23 >> 16);
  }
  // ---- v transpose into LDS ----
  if (tid < 216) {
#pragma unroll
    for (int j = 0; j < 8; ++j) vT[vc + j][vr] = (unsigned short)vv[j];
  }
  __syncthreads();
  // ---- O = P @ V ----
  f32x4 oac[2];
  oac[0] = (f32x4){0.f, 0.f, 0.f, 0.f};
  oac[1] = (f32x4){0.f, 0.f, 0.f, 0.f};
#pragma unroll
  for (int k2 = 0; k2 < 2; ++k2) {
    short8 pa = *(const short8*)&Ps[arow][k2 * 32 + g * 8];
#pragma unroll
    for (int tn = 0; tn < 2; ++tn) {
      short8 vb = *(const short8*)&vT[tn * 16 + lc][k2 * 32 + g * 8];
      oac[tn] = __builtin_amdgcn_mfma_f32_16x16x32_bf16(pa, vb, oac[tn], 0, 0, 0);
    }
  }
  // write O over this block's own Q slab (q is dead after QK^T)
#pragma unroll
  for (int tn = 0; tn < 2; ++tn) {
    const int d = tn * 16 + lc;
    const unsigned int u01 = cvtpk(oac[tn][0], oac[tn][1]);
    const unsigned int u23 = cvtpk(oac[tn][2], oac[tn][3]);
    unsigned short* p = &Qh[(base + row0) * 32 + d];
    if (row0 < NT)     p[0]  = (unsigned short)(u01 & 0xffffu);
    if (row0 + 1 < NT) p[32] = (unsigned short)(u01 >> 16);
    if (row0 + 2 < NT) p[64] = (unsigned short)(u23 & 0xffffu);
    if (row0 + 3 < NT) p[96] = (unsigned short)(u23 >> 16);
  }
}

// proj GEMM over h-major A (the O planes) — R6-proven reg-staged 2-barrier.
// out[m][n]=sum_k A[m][k]*Wp[n][k]+b;  A[m][h*32+d] = AO[h*HS + m*32 + d]
// grid = 2592 = 8 xcd * 108 m * 3 n
__global__ __launch_bounds__(256) void proj_hmajor(
    const unsigned short* __restrict__ AO, const unsigned short* __restrict__ Wp,
    const float* __restrict__ proj_b, float* __restrict__ out) {
  __shared__ unsigned short As[128][72];
  __shared__ unsigned short Bs[128][72];
  const int s = blockIdx.x;
  const int xcd = s & 7, slot = s >> 3;
  const size_t m0 = (size_t)(xcd * 108 + slot / 3) * 128;
  const int n0 = (slot % 3) * 128;
  const int tid = threadIdx.x;
  const int wv = tid >> 6, ln = tid & 63, g = ln >> 4, lc = ln & 15;
  const int wr = (wv >> 1) * 64, wc = (wv & 1) * 64;
  f32x4 acc[4][4];
#pragma unroll
  for (int i = 0; i < 4; ++i)
#pragma unroll
    for (int j = 0; j < 4; ++j) acc[i][j] = (f32x4){0.f, 0.f, 0.f, 0.f};

  const int srow = tid >> 3, l8 = tid & 7;
  for (int kc = 0; kc < 6; ++kc) {
    const int k0 = kc * 64;
    const int kg = k0 + l8 * 8;
    const int hh = kg >> 5, dd = kg & 31;         // 8-chunk stays in one head
#pragma unroll
    for (int it = 0; it < 4; ++it) {
      const int r = srow + it * 32;
      *(short8*)&As[r][l8 * 8] =
          *(const short8*)&AO[(size_t)hh * HS + (m0 + r) * 32 + dd];
      *(short8*)&Bs[r][l8 * 8] =
          *(const short8*)&Wp[(size_t)(n0 + r) * 384 + kg];
    }
    __syncthreads();
#pragma unroll
    for (int kk = 0; kk < 2; ++kk) {
      short8 af[4], bfv[4];
#pragma unroll
      for (int ms = 0; ms < 4; ++ms)
        af[ms] = *(const short8*)&As[wr + ms * 16 + lc][kk * 32 + g * 8];
#pragma unroll
      for (int ns = 0; ns < 4; ++ns)
        bfv[ns] = *(const short8*)&Bs[wc + ns * 16 + lc][kk * 32 + g * 8];
#pragma unroll
      for (int ms = 0; ms < 4; ++ms)
#pragma unroll
        for (int ns = 0; ns < 4; ++ns)
          acc[ms][ns] = __builtin_amdgcn_mfma_f32_16x16x32_bf16(
              af[ms], bfv[ns], acc[ms][ns], 0, 0, 0);
    }
    __syncthreads();
  }
#pragma unroll
  for (int ns = 0; ns < 4; ++ns) {
    const int n = n0 + wc + ns * 16 + lc;
    const float pb = proj_b[n];
#pragma unroll
    for (int ms = 0; ms < 4; ++ms)
#pragma unroll
      for (int rr = 0; rr < 4; ++rr) {
        const size_t m = m0 + wr + ms * 16 + g * 4 + rr;
        out[m * 384 + n] = acc[ms][ns][rr] + pb;
      }
  }
}

// ================================================= FALLBACK (round-1) =====
__global__ __launch_bounds__(256) void prep_kernel(
    const float* __restrict__ qkv_w, const float* __restrict__ proj_w,
    const float* __restrict__ mask, const float* __restrict__ rpb,
    const int* __restrict__ rel,
    unsigned short* __restrict__ Wq, unsigned short* __restrict__ Wp,
    float* __restrict__ bias_tab, float* __restrict__ maskp) {
  int idx = blockIdx.x * 256 + threadIdx.x;
  if (idx < 1152 * 384) { Wq[idx] = f2bf(qkv_w[idx]); return; }
  idx -= 1152 * 384;
  if (idx < 384 * 384) { Wp[idx] = f2bf(proj_w[idx]); return; }
  idx -= 384 * 384;
  if (idx < NH * 64 * 64) {
    int h = idx >> 12, r = (idx >> 6) & 63, c = idx & 63;
    float v;
    if (r >= NT || c >= NT) v = -1e30f;
    else if (r >= 5 && c >= 5) v = rpb[rel[(r - 5) * 49 + (c - 5)] * NH + h];
    else v = 0.0f;
    bias_tab[idx] = v;
    return;
  }
  idx -= NH * 64 * 64;
  if (idx < NWIN * 64 * 64) {
    int w = idx >> 12, r = (idx >> 6) & 63, c = idx & 63;
    float v = 0.0f;
    if (r >= 5 && r < NT && c >= 5 && c < NT)
      v = mask[w * 2401 + (r - 5) * 49 + (c - 5)];
    maskp[idx] = v;
  }
}

__global__ __launch_bounds__(256) void fused_attn(
    const float* __restrict__ x, const unsigned short* __restrict__ Wq,
    const float* __restrict__ qkv_b, const float* __restrict__ bias_tab,
    const float* __restrict__ maskp, unsigned short* __restrict__ AO) {
  __shared__ unsigned short xs[NT][392];
  __shared__ unsigned short qs[NT][40];
  __shared__ unsigned short ksm[NT][40];
  __shared__ unsigned short vT[32][72];
  __shared__ unsigned short Ps[NT][72];
  const int b = blockIdx.x;
  const int tid = threadIdx.x;
  const int wv = tid >> 6, ln = tid & 63;
  const int g = ln >> 4, lc = ln & 15;
  const int m0 = wv * 16;
  const int wi = b & 63;
  const float scale = 0.17677669529663687f;
  const float* xb = x + (size_t)b * (NT * DIM);
  for (int i = tid; i < NT * DIM / 4; i += 256) {
    float4 v = ((const float4*)xb)[i];
    int e = i * 4, r = e / DIM, c = e - r * DIM;
    unsigned short* p = &xs[r][c];
    p[0] = f2bf(v.x); p[1] = f2bf(v.y); p[2] = f2bf(v.z); p[3] = f2bf(v.w);
  }
  __syncthreads();
  const int arow = (m0 + lc < NT) ? (m0 + lc) : (NT - 1);
  for (int h = 0; h < NH; ++h) {
    f32x4 acc[6];
#pragma unroll
    for (int t = 0; t < 6; ++t) acc[t] = (f32x4){0.f, 0.f, 0.f, 0.f};
#pragma unroll 2
    for (int kk = 0; kk < 12; ++kk) {
      short8 a = *(const short8*)&xs[arow][kk * 32 + g * 8];
#pragma unroll
      for (int t = 0; t < 6; ++t) {
        const int sel = t >> 1;
        const int wrow = sel * 384 + h * 32 + (t & 1) * 16 + lc;
        short8 bfr = *(const short8*)&Wq[wrow * 384 + kk * 32 + g * 8];
        acc[t] = __builtin_amdgcn_mfma_f32_16x16x32_bf16(a, bfr, acc[t], 0, 0, 0);
      }
    }
#pragma unroll
    for (int t = 0; t < 6; ++t) {
      const int sel = t >> 1;
      const int d = (t & 1) * 16 + lc;
      const float bias = qkv_b[sel * 384 + h * 32 + d];
#pragma unroll
      for (int r = 0; r < 4; ++r) {
        const int m = m0 + g * 4 + r;
        float v = acc[t][r] + bias;
        if (sel == 2) vT[d][m] = f2bf(v);
        else if (m < NT) {
          if (sel == 0) qs[m][d] = f2bf(v * scale);
          else ksm[m][d] = f2bf(v);
        }
      }
    }
    __syncthreads();
    f32x4 sac[4];
    {
      short8 a = *(const short8*)&qs[arow][g * 8];
#pragma unroll
      for (int t = 0; t < 4; ++t) {
        const int kr = (t * 16 + lc < NT) ? (t * 16 + lc) : (NT - 1);
        short8 bfr = *(const short8*)&ksm[kr][g * 8];
        sac[t] = __builtin_amdgcn_mfma_f32_16x16x32_bf16(
            a, bfr, (f32x4){0.f, 0.f, 0.f, 0.f}, 0, 0, 0);
      }
    }
    const float* bt = bias_tab + h * 4096;
    const float* mp = maskp + wi * 4096;
    float sv[4][4];
    float rmax[4];
#pragma unroll
    for (int r = 0; r < 4; ++r) rmax[r] = -3.0e38f;
#pragma unroll
    for (int t = 0; t < 4; ++t) {
      const int col = t * 16 + lc;
#pragma unroll
      for (int r = 0; r < 4; ++r) {
        const int row = m0 + g * 4 + r;
        float s2 = sac[t][r] + bt[row * 64 + col] + mp[row * 64 + col];
        sv[t][r] = s2;
        rmax[r] = fmaxf(rmax[r], s2);
      }
    }
#pragma unroll
    for (int r = 0; r < 4; ++r)
#pragma unroll
      for (int off = 1; off < 16; off <<= 1)
        rmax[r] = fmaxf(rmax[r], __shfl_xor(rmax[r], off));
    float rsum[4] = {0.f, 0.f, 0.f, 0.f};
#pragma unroll
    for (int t = 0; t < 4; ++t)
#pragma unroll
      for (int r = 0; r < 4; ++r) {
        float p = __expf(sv[t][r] - rmax[r]);
        sv[t][r] = p;
        rsum[r] += p;
      }
#pragma unroll
    for (int r = 0; r < 4; ++r) {
#pragma unroll
      for (int off = 1; off < 16; off <<= 1)
        rsum[r] += __shfl_xor(rsum[r], off);
      rsum[r] = 1.0f / rsum[r];
    }
#pragma unroll
    for (int t = 0; t < 4; ++t) {
      const int col = t * 16 + lc;
#pragma unroll
      for (int r = 0; r < 4; ++r) {
        const int row = m0 + g * 4 + r;
        if (row < NT) Ps[row][col] = f2bf(sv[t][r] * rsum[r]);
      }
    }
    __syncthreads();
    f32x4 oac[2];
    oac[0] = (f32x4){0.f, 0.f, 0.f, 0.f};
    oac[1] = (f32x4){0.f, 0.f, 0.f, 0.f};
#pragma unroll
    for (int k2 = 0; k2 < 2; ++k2) {
      short8 a = *(const short8*)&Ps[arow][k2 * 32 + g * 8];
#pragma unroll
      for (int tn = 0; tn < 2; ++tn) {
        short8 bfr = *(const short8*)&vT[tn * 16 + lc][k2 * 32 + g * 8];
        oac[tn] = __builtin_amdgcn_mfma_f32_16x16x32_bf16(a, bfr, oac[tn], 0, 0, 0);
      }
    }
    unsigned short* aob = AO + (size_t)b * (NT * DIM) + h * 32;
#pragma unroll
    for (int tn = 0; tn < 2; ++tn) {
      const int d = tn * 16 + lc;
#pragma unroll
      for (int r = 0; r < 4; ++r) {
        const int m = m0 + g * 4 + r;
        if (m < NT) aob[m * DIM + d] = f2bf(oac[tn][r]);
      }
    }
    __syncthreads();
  }
}

__global__ __launch_bounds__(256) void proj_kernel(
    const unsigned short* __restrict__ AO, const unsigned short* __restrict__ Wp,
    const float* __restrict__ proj_b, float* __restrict__ out, int lda) {
  __shared__ unsigned short As[128][72];
  __shared__ unsigned short Bs[128][72];
  const int s = blockIdx.x;
  const int xcd = s & 7, slot = s >> 3;
  const size_t m0 = (size_t)(xcd * 108 + slot / 3) * 128;
  const int n0 = (slot % 3) * 128;
  const int tid = threadIdx.x;
  const int wv = tid >> 6, ln = tid & 63, g = ln >> 4, lc = ln & 15;
  const int wr = (wv >> 1) * 64, wc = (wv & 1) * 64;
  f32x4 acc[4][4];
#pragma unroll
  for (int i = 0; i < 4; ++i)
#pragma unroll
    for (int j = 0; j < 4; ++j) acc[i][j] = (f32x4){0.f, 0.f, 0.f, 0.f};

  const int srow = tid >> 3, l8 = tid & 7;
  for (int kc = 0; kc < 6; ++kc) {
    const int k0 = kc * 64;
#pragma unroll
    for (int it = 0; it < 4; ++it) {
      const int r = srow + it * 32;
      *(short8*)&As[r][l8 * 8] =
          *(const short8*)&AO[(m0 + r) * (size_t)lda + k0 + l8 * 8];
      *(short8*)&Bs[r][l8 * 8] =
          *(const short8*)&Wp[(size_t)(n0 + r) * 384 + k0 + l8 * 8];
    }
    __syncthreads();
#pragma unroll
    for (int kk = 0; kk < 2; ++kk) {
      short8 af[4], bfr[4];
#pragma unroll
      for (int ms = 0; ms < 4; ++ms)
        af[ms] = *(const short8*)&As[wr + ms * 16 + lc][kk * 32 + g * 8];
#pragma unroll
      for (int ns = 0; ns < 4; ++ns)
        bfr[ns] = *(const short8*)&Bs[wc + ns * 16 + lc][kk * 32 + g * 8];
#pragma unroll
      for (int ms = 0; ms < 4; ++ms)
#pragma unroll
        for (int ns = 0; ns < 4; ++ns)
          acc[ms][ns] = __builtin_amdgcn_mfma_f32_16x16x32_bf16(
              af[ms], bfr[ns], acc[ms][ns], 0, 0, 0);
    }
    __syncthreads();
  }
#pragma unroll
  for (int ns = 0; ns < 4; ++ns) {
    const int n = n0 + wc + ns * 16 + lc;
    const float pb = proj_b[n];
#pragma unroll
    for (int ms = 0; ms < 4; ++ms)
#pragma unroll
      for (int rr = 0; rr < 4; ++rr) {
        const size_t m = m0 + wr + ms * 16 + g * 4 + rr;
        out[m * 384 + n] = acc[ms][ns][rr] + pb;
      }
  }
}

// -------------------------------------------------------------- launch ----
extern "C" void kernel_launch(void* const* d_in, const int* in_sizes, int n_in,
                              void* d_out, int out_size, void* d_ws, size_t ws_size,
                              hipStream_t stream) {
  const float* x      = (const float*)d_in[0];
  const float* mask   = (const float*)d_in[1];
  const float* qkv_w  = (const float*)d_in[2];
  const float* qkv_b  = (const float*)d_in[3];
  const float* proj_w = (const float*)d_in[4];
  const float* proj_b = (const float*)d_in[5];
  const float* rpb    = (const float*)d_in[6];
  const int*   rel    = (const int*)d_in[7];
  float* out = (float*)d_out;

  const size_t QKV_ELEMS = (size_t)3 * NH * HS;  // 127,401,984
  const size_t WQ_ELEMS = 1152 * 384, WP_ELEMS = 384 * 384;
  const size_t BMT_ELEMS = (size_t)NWIN * NH * 4096;
  const size_t need = (QKV_ELEMS + WQ_ELEMS + WP_ELEMS + BMT_ELEMS) * 2;

  if (ws_size >= need) {
    // -------- fast path: h-major Q/K/V planes --------
    unsigned short* Qb  = (unsigned short*)d_ws;
    unsigned short* Kb  = Qb + NH * HS;
    unsigned short* Vb  = Kb + NH * HS;
    unsigned short* Wq  = Vb + NH * HS;
    unsigned short* Wp  = Wq + WQ_ELEMS;
    unsigned short* bmt = Wp + WP_ELEMS;

    prep2_kernel<<<14592, 256, 0, stream>>>(qkv_w, proj_w, mask, rpb, rel,
                                            Wq, Wp, bmt);
    qkv_gemm6<<<7776, 256, 0, stream>>>(x, Wq, qkv_b, Qb, Kb, Vb);
    attn2_kernel<<<24576, 256, 0, stream>>>(Qb, Kb, Vb, bmt);
    proj_hmajor<<<2592, 256, 0, stream>>>(Qb, Wp, proj_b, out);
  } else {
    // -------- fallback: round-1 fused path (88 MB scratch) --------
    unsigned short* Wq = (unsigned short*)d_ws;
    unsigned short* Wp = Wq + 442368;
    float* bias_tab = (float*)(Wp + 147456);
    float* maskp = bias_tab + 12 * 64 * 64;
    unsigned short* AO = (unsigned short*)(maskp + 64 * 64 * 64);
    prep_kernel<<<3520, 256, 0, stream>>>(qkv_w, proj_w, mask, rpb, rel,
                                          Wq, Wp, bias_tab, maskp);
    fused_attn<<<2048, 256, 0, stream>>>(x, Wq, qkv_b, bias_tab, maskp, AO);
    proj_kernel<<<2592, 256, 0, stream>>>(AO, Wp, proj_b, out, 384);
  }
}

// Round 14
// 450.808 us; speedup vs baseline: 1.0277x; 1.0277x over previous
//
#include <hip/hip_runtime.h>

#define DIM 384
#define NH 12
#define NT 54   // 49 window + 5 prompt tokens
#define NWIN 64
#define MTOT 110592             // 2048 * 54
#define HS ((size_t)MTOT * 32)  // per-head plane size (Q/K: [m][32], VT: [32][m])

typedef __attribute__((ext_vector_type(8))) short short8;
typedef __attribute__((ext_vector_type(4))) float f32x4;

__device__ __forceinline__ unsigned short f2bf(float f) {
  unsigned int u = __float_as_uint(f);
  u += 0x7fffu + ((u >> 16) & 1u);   // round-to-nearest-even
  return (unsigned short)(u >> 16);
}
__device__ __forceinline__ float bf2f(unsigned short s) {
  return __uint_as_float((unsigned int)s << 16);
}
// packed f32->bf16 (RTNE, same result as f2bf): D.lo=bf16(a), D.hi=bf16(b)
__device__ __forceinline__ unsigned int cvtpk(float a, float b) {
  unsigned int r;
  asm("v_cvt_pk_bf16_f32 %0, %1, %2" : "=v"(r) : "v"(a), "v"(b));
  return r;
}
// async global->LDS, 16B per lane; LDS dest = wave-uniform base + lane*16
__device__ __forceinline__ void gload16(const unsigned short* g,
                                        unsigned short* l) {
  __builtin_amdgcn_global_load_lds(
      (const __attribute__((address_space(1))) void*)g,
      (__attribute__((address_space(3))) void*)l, 16, 0, 0);
}

// ===================================================== FAST PATH ==========
// convert_x: x fp32 -> bf16 into d_out (dead space until proj writes it)
__global__ __launch_bounds__(256) void convert_x(
    const float* __restrict__ x, unsigned short* __restrict__ xb) {
  const size_t i8 = ((size_t)blockIdx.x * 256 + threadIdx.x) * 8;
  float4 fa = *(const float4*)&x[i8];
  float4 fb = *(const float4*)&x[i8 + 4];
  uint4 u;
  u.x = cvtpk(fa.x, fa.y);
  u.y = cvtpk(fa.z, fa.w);
  u.z = cvtpk(fb.x, fb.y);
  u.w = cvtpk(fb.z, fb.w);
  *(uint4*)&xb[i8] = u;
}

// prep2: weights -> bf16; combined bias+mask table bmt in TRANSPOSED layout
// bmt[w][h][col][row] bf16: -1e30 in pad rows/cols, bias+mask elsewhere
__global__ __launch_bounds__(256) void prep2_kernel(
    const float* __restrict__ qkv_w, const float* __restrict__ proj_w,
    const float* __restrict__ mask, const float* __restrict__ rpb,
    const int* __restrict__ rel,
    unsigned short* __restrict__ Wq, unsigned short* __restrict__ Wp,
    unsigned short* __restrict__ bmt) {
  int idx = blockIdx.x * 256 + threadIdx.x;
  if (idx < 1152 * 384) { Wq[idx] = f2bf(qkv_w[idx]); return; }
  idx -= 1152 * 384;
  if (idx < 384 * 384) { Wp[idx] = f2bf(proj_w[idx]); return; }
  idx -= 384 * 384;
  if (idx < NWIN * NH * 64 * 64) {
    int w = idx / (NH * 4096);
    int rem = idx - w * (NH * 4096);
    int h = rem >> 12, r = (rem >> 6) & 63, c = rem & 63;
    float v;
    if (r >= NT || c >= NT) v = -1e30f;
    else if (r >= 5 && c >= 5)
      v = rpb[rel[(r - 5) * 49 + (c - 5)] * NH + h] +
          mask[w * 2401 + (r - 5) * 49 + (c - 5)];
    else v = 0.0f;
    // transposed store: [w][h][c][r]
    bmt[w * (NH * 4096) + (h << 12) + (c << 6) + r] = f2bf(v);
  }
}

// QKV GEMM (R10-proven gload_lds + XOR swizzle, 2-barrier). Epilogue writes
// Q,K as [h][m][32] and V TRANSPOSED as VT[h][d][m] (8B contiguous stores)
// so attention's PV B-fragments load straight from global.
// grid = 7776 = 8 xcd * 108 m * 9 n.  C[m][n] = xb[m][k]*Wq[n][k]+b[n]
__global__ __launch_bounds__(256) void qkv_gemm5(
    const unsigned short* __restrict__ xb, const unsigned short* __restrict__ Wq,
    const float* __restrict__ qkv_b,
    unsigned short* __restrict__ Qb, unsigned short* __restrict__ Kb,
    unsigned short* __restrict__ VT) {
  __shared__ unsigned short As[128][64];
  __shared__ unsigned short Bs[128][64];
  const int s = blockIdx.x;
  const int xcd = s & 7, slot = s >> 3;
  const size_t m0 = (size_t)(xcd * 108 + slot / 9) * 128;
  const int n0 = (slot % 9) * 128;
  const int tid = threadIdx.x;
  const int wv = tid >> 6, ln = tid & 63, g = ln >> 4, lc = ln & 15;
  const int wr = (wv >> 1) * 64, wc = (wv & 1) * 64;
  const int l7 = lc & 7;
  const int lr8 = ln >> 3;                       // row-in-8 for staging
  const int sc8 = (((ln & 7) ^ lr8) & 7) * 8;    // swizzled source chunk (elems)

  f32x4 acc[4][4];
#pragma unroll
  for (int i = 0; i < 4; ++i)
#pragma unroll
    for (int j = 0; j < 4; ++j) acc[i][j] = (f32x4){0.f, 0.f, 0.f, 0.f};

#pragma unroll
  for (int kc = 0; kc < 6; ++kc) {
    const int k0 = kc * 64;
    if (kc) __syncthreads();          // all waves done reading prev tile
#pragma unroll
    for (int it = 0; it < 4; ++it) {  // wave stages rows wv*32 .. wv*32+31
      const int r0 = wv * 32 + it * 8;
      const int r = r0 + lr8;
      gload16(&xb[(m0 + r) * 384 + k0 + sc8], &As[r0][0]);
      gload16(&Wq[(size_t)(n0 + r) * 384 + k0 + sc8], &Bs[r0][0]);
    }
    __syncthreads();                  // drains vmcnt(0) -> tile visible
#pragma unroll
    for (int kk = 0; kk < 2; ++kk) {
      const int cix = (((kk * 4 + g) ^ l7)) * 8;   // swizzled read chunk
      short8 af[4], bfv[4];
#pragma unroll
      for (int ms = 0; ms < 4; ++ms)
        af[ms] = *(const short8*)&As[wr + ms * 16 + lc][cix];
#pragma unroll
      for (int ns = 0; ns < 4; ++ns)
        bfv[ns] = *(const short8*)&Bs[wc + ns * 16 + lc][cix];
#pragma unroll
      for (int ms = 0; ms < 4; ++ms)
#pragma unroll
        for (int ns = 0; ns < 4; ++ns)
          acc[ms][ns] = __builtin_amdgcn_mfma_f32_16x16x32_bf16(
              af[ms], bfv[ns], acc[ms][ns], 0, 0, 0);
    }
  }

  const int sel = n0 / 384;                       // 384 = 3*128, no crossing
  const float factor = (sel == 0) ? 0.17677669529663687f : 1.0f;
#pragma unroll
  for (int ns = 0; ns < 4; ++ns) {
    const int n = n0 + wc + ns * 16 + lc;
    const int rl = n - sel * 384;
    const int h = rl >> 5, d = rl & 31;           // 16-chunk stays in one head
    const float bias = qkv_b[n];
#pragma unroll
    for (int ms = 0; ms < 4; ++ms) {
      const size_t mrow = m0 + wr + ms * 16 + g * 4;
      const float v0 = (acc[ms][ns][0] + bias) * factor;
      const float v1 = (acc[ms][ns][1] + bias) * factor;
      const float v2 = (acc[ms][ns][2] + bias) * factor;
      const float v3 = (acc[ms][ns][3] + bias) * factor;
      const unsigned int u01 = cvtpk(v0, v1);
      const unsigned int u23 = cvtpk(v2, v3);
      if (sel == 2) {
        // VT[h][d][m]: 4 consecutive m -> one 8B store (mrow%4==0 -> aligned)
        unsigned short* p = &VT[((size_t)h * 32 + d) * MTOT + mrow];
        uint2 u2; u2.x = u01; u2.y = u23;
        *(uint2*)p = u2;
      } else {
        unsigned short* outp = (sel == 0) ? Qb : Kb;
        unsigned short* p = &outp[(size_t)h * HS + mrow * 32 + d];
        p[0]  = (unsigned short)(u01 & 0xffffu);
        p[32] = (unsigned short)(u01 >> 16);
        p[64] = (unsigned short)(u23 & 0xffffu);
        p[96] = (unsigned short)(u23 >> 16);
      }
    }
  }
}

// attention v4: BARRIER-FREE. V^T plane read direct from global as PV
// B-fragments (no vT LDS, no transpose, no __syncthreads — Ps is per-wave
// private, same-wave ds ordering via lgkmcnt). Pad cols k>=54: P==0 exactly
// (bias -1e30), V^T pad reads are in-ws finite bf16 -> 0*finite = 0.
// w-locality XCD mapping keeps bmt slab (768 KB) L2-resident.
// grid = 24576 = 8 xcd * (8 wl * 32 batch * 12 h)
__global__ __launch_bounds__(256) void attn4_kernel(
    unsigned short* __restrict__ Qb, const unsigned short* __restrict__ Kb,
    const unsigned short* __restrict__ VT, const unsigned short* __restrict__ bmt) {
  __shared__ unsigned short Ps[NT][72];
  const int s = blockIdx.x;
  const int xcd = s & 7, r3 = s >> 3;       // r3 in [0,3072)
  const int h = r3 % 12;
  const int t2 = r3 / 12;                    // [0,256)
  const int batch = t2 & 31;
  const int w = xcd * 8 + (t2 >> 5);         // this XCD's 8 windows
  const int b = batch * 64 + w;
  const int tid = threadIdx.x;
  const int wv = tid >> 6, ln = tid & 63, g = ln >> 4, lc = ln & 15;
  const int m0 = wv * 16;
  const size_t base = (size_t)b * NT;
  const int arow = (m0 + lc < NT) ? (m0 + lc) : (NT - 1);
  unsigned short* Qh = Qb + (size_t)h * HS;
  const unsigned short* Kh = Kb + (size_t)h * HS;
  const unsigned short* VTh = VT + (size_t)h * 32 * MTOT;

  // ---- hoisted loads: q, k[4], bias+mask[4] ----
  short8 a = *(const short8*)&Qh[(base + arow) * 32 + g * 8];
  const unsigned short* bmh = &bmt[(size_t)(w * NH + h) << 12];  // [c][r]
  const int row0 = m0 + g * 4;
  short8 kb[4];
  uint2 uu[4];
#pragma unroll
  for (int t = 0; t < 4; ++t) {
    const int col = t * 16 + lc;
    const int kr = (col < NT) ? col : (NT - 1);
    kb[t] = *(const short8*)&Kh[(base + kr) * 32 + g * 8];
    uu[t] = *(const uint2*)&bmh[(col << 6) + row0];  // 4 bf16 rows r0..r0+3
  }

  // ---- S = q@k^T with C initialized from transposed bias+mask table ----
  f32x4 sac[4];
#pragma unroll
  for (int t = 0; t < 4; ++t) {
    f32x4 c0;
    c0[0] = bf2f((unsigned short)(uu[t].x & 0xffffu));
    c0[1] = bf2f((unsigned short)(uu[t].x >> 16));
    c0[2] = bf2f((unsigned short)(uu[t].y & 0xffffu));
    c0[3] = bf2f((unsigned short)(uu[t].y >> 16));
    sac[t] = __builtin_amdgcn_mfma_f32_16x16x32_bf16(a, kb[t], c0, 0, 0, 0);
  }
  // ---- row softmax (16-lane groups own rows) ----
  float rmax[4] = {-3.0e38f, -3.0e38f, -3.0e38f, -3.0e38f};
#pragma unroll
  for (int t = 0; t < 4; ++t)
#pragma unroll
    for (int rr = 0; rr < 4; ++rr) rmax[rr] = fmaxf(rmax[rr], sac[t][rr]);
#pragma unroll
  for (int rr = 0; rr < 4; ++rr)
#pragma unroll
    for (int off = 1; off < 16; off <<= 1)
      rmax[rr] = fmaxf(rmax[rr], __shfl_xor(rmax[rr], off));
  float rsum[4] = {0.f, 0.f, 0.f, 0.f};
#pragma unroll
  for (int t = 0; t < 4; ++t)
#pragma unroll
    for (int rr = 0; rr < 4; ++rr) {
      float p = __expf(sac[t][rr] - rmax[rr]);
      sac[t][rr] = p;
      rsum[rr] += p;
    }
#pragma unroll
  for (int rr = 0; rr < 4; ++rr) {
#pragma unroll
    for (int off = 1; off < 16; off <<= 1)
      rsum[rr] += __shfl_xor(rsum[rr], off);
    rsum[rr] = 1.0f / rsum[rr];
  }
#pragma unroll
  for (int t = 0; t < 4; ++t) {
    const int col = t * 16 + lc;
    const unsigned int u01 = cvtpk(sac[t][0] * rsum[0], sac[t][1] * rsum[1]);
    const unsigned int u23 = cvtpk(sac[t][2] * rsum[2], sac[t][3] * rsum[3]);
    if (row0 < NT)     Ps[row0][col]     = (unsigned short)(u01 & 0xffffu);
    if (row0 + 1 < NT) Ps[row0 + 1][col] = (unsigned short)(u01 >> 16);
    if (row0 + 2 < NT) Ps[row0 + 2][col] = (unsigned short)(u23 & 0xffffu);
    if (row0 + 3 < NT) Ps[row0 + 3][col] = (unsigned short)(u23 >> 16);
  }
  // NO barrier: Ps strip is wave-private (rows m0..m0+15); lgkmcnt orders
  // the ds_write -> ds_read within the wave; LDS data is lane-shared.

  // ---- O = P @ V, V^T B-fragments straight from global ----
  f32x4 oac[2];
  oac[0] = (f32x4){0.f, 0.f, 0.f, 0.f};
  oac[1] = (f32x4){0.f, 0.f, 0.f, 0.f};
#pragma unroll
  for (int k2 = 0; k2 < 2; ++k2) {
    short8 pa = *(const short8*)&Ps[arow][k2 * 32 + g * 8];
#pragma unroll
    for (int tn = 0; tn < 2; ++tn) {
      short8 vb = *(const short8*)&VTh[(size_t)(tn * 16 + lc) * MTOT + base +
                                       k2 * 32 + g * 8];
      oac[tn] = __builtin_amdgcn_mfma_f32_16x16x32_bf16(pa, vb, oac[tn], 0, 0, 0);
    }
  }
  // write O over this block's own Q slab (q is dead after QK^T)
#pragma unroll
  for (int tn = 0; tn < 2; ++tn) {
    const int d = tn * 16 + lc;
    const unsigned int u01 = cvtpk(oac[tn][0], oac[tn][1]);
    const unsigned int u23 = cvtpk(oac[tn][2], oac[tn][3]);
    unsigned short* p = &Qh[(base + row0) * 32 + d];
    if (row0 < NT)     p[0]  = (unsigned short)(u01 & 0xffffu);
    if (row0 + 1 < NT) p[32] = (unsigned short)(u01 >> 16);
    if (row0 + 2 < NT) p[64] = (unsigned short)(u23 & 0xffffu);
    if (row0 + 3 < NT) p[96] = (unsigned short)(u23 >> 16);
  }
}

// proj GEMM over h-major A (the O planes) — R6-proven reg-staged 2-barrier.
// out[m][n]=sum_k A[m][k]*Wp[n][k]+b;  A[m][h*32+d] = AO[h*HS + m*32 + d]
// grid = 2592 = 8 xcd * 108 m * 3 n
__global__ __launch_bounds__(256) void proj_hmajor(
    const unsigned short* __restrict__ AO, const unsigned short* __restrict__ Wp,
    const float* __restrict__ proj_b, float* __restrict__ out) {
  __shared__ unsigned short As[128][72];
  __shared__ unsigned short Bs[128][72];
  const int s = blockIdx.x;
  const int xcd = s & 7, slot = s >> 3;
  const size_t m0 = (size_t)(xcd * 108 + slot / 3) * 128;
  const int n0 = (slot % 3) * 128;
  const int tid = threadIdx.x;
  const int wv = tid >> 6, ln = tid & 63, g = ln >> 4, lc = ln & 15;
  const int wr = (wv >> 1) * 64, wc = (wv & 1) * 64;
  f32x4 acc[4][4];
#pragma unroll
  for (int i = 0; i < 4; ++i)
#pragma unroll
    for (int j = 0; j < 4; ++j) acc[i][j] = (f32x4){0.f, 0.f, 0.f, 0.f};

  const int srow = tid >> 3, l8 = tid & 7;
  for (int kc = 0; kc < 6; ++kc) {
    const int k0 = kc * 64;
    const int kg = k0 + l8 * 8;
    const int hh = kg >> 5, dd = kg & 31;         // 8-chunk stays in one head
#pragma unroll
    for (int it = 0; it < 4; ++it) {
      const int r = srow + it * 32;
      *(short8*)&As[r][l8 * 8] =
          *(const short8*)&AO[(size_t)hh * HS + (m0 + r) * 32 + dd];
      *(short8*)&Bs[r][l8 * 8] =
          *(const short8*)&Wp[(size_t)(n0 + r) * 384 + kg];
    }
    __syncthreads();
#pragma unroll
    for (int kk = 0; kk < 2; ++kk) {
      short8 af[4], bfv[4];
#pragma unroll
      for (int ms = 0; ms < 4; ++ms)
        af[ms] = *(const short8*)&As[wr + ms * 16 + lc][kk * 32 + g * 8];
#pragma unroll
      for (int ns = 0; ns < 4; ++ns)
        bfv[ns] = *(const short8*)&Bs[wc + ns * 16 + lc][kk * 32 + g * 8];
#pragma unroll
      for (int ms = 0; ms < 4; ++ms)
#pragma unroll
        for (int ns = 0; ns < 4; ++ns)
          acc[ms][ns] = __builtin_amdgcn_mfma_f32_16x16x32_bf16(
              af[ms], bfv[ns], acc[ms][ns], 0, 0, 0);
    }
    __syncthreads();
  }
#pragma unroll
  for (int ns = 0; ns < 4; ++ns) {
    const int n = n0 + wc + ns * 16 + lc;
    const float pb = proj_b[n];
#pragma unroll
    for (int ms = 0; ms < 4; ++ms)
#pragma unroll
      for (int rr = 0; rr < 4; ++rr) {
        const size_t m = m0 + wr + ms * 16 + g * 4 + rr;
        out[m * 384 + n] = acc[ms][ns][rr] + pb;
      }
  }
}

// ================================================= FALLBACK (round-1) =====
__global__ __launch_bounds__(256) void prep_kernel(
    const float* __restrict__ qkv_w, const float* __restrict__ proj_w,
    const float* __restrict__ mask, const float* __restrict__ rpb,
    const int* __restrict__ rel,
    unsigned short* __restrict__ Wq, unsigned short* __restrict__ Wp,
    float* __restrict__ bias_tab, float* __restrict__ maskp) {
  int idx = blockIdx.x * 256 + threadIdx.x;
  if (idx < 1152 * 384) { Wq[idx] = f2bf(qkv_w[idx]); return; }
  idx -= 1152 * 384;
  if (idx < 384 * 384) { Wp[idx] = f2bf(proj_w[idx]); return; }
  idx -= 384 * 384;
  if (idx < NH * 64 * 64) {
    int h = idx >> 12, r = (idx >> 6) & 63, c = idx & 63;
    float v;
    if (r >= NT || c >= NT) v = -1e30f;
    else if (r >= 5 && c >= 5) v = rpb[rel[(r - 5) * 49 + (c - 5)] * NH + h];
    else v = 0.0f;
    bias_tab[idx] = v;
    return;
  }
  idx -= NH * 64 * 64;
  if (idx < NWIN * 64 * 64) {
    int w = idx >> 12, r = (idx >> 6) & 63, c = idx & 63;
    float v = 0.0f;
    if (r >= 5 && r < NT && c >= 5 && c < NT)
      v = mask[w * 2401 + (r - 5) * 49 + (c - 5)];
    maskp[idx] = v;
  }
}

__global__ __launch_bounds__(256) void fused_attn(
    const float* __restrict__ x, const unsigned short* __restrict__ Wq,
    const float* __restrict__ qkv_b, const float* __restrict__ bias_tab,
    const float* __restrict__ maskp, unsigned short* __restrict__ AO) {
  __shared__ unsigned short xs[NT][392];
  __shared__ unsigned short qs[NT][40];
  __shared__ unsigned short ksm[NT][40];
  __shared__ unsigned short vT[32][72];
  __shared__ unsigned short Ps[NT][72];
  const int b = blockIdx.x;
  const int tid = threadIdx.x;
  const int wv = tid >> 6, ln = tid & 63;
  const int g = ln >> 4, lc = ln & 15;
  const int m0 = wv * 16;
  const int wi = b & 63;
  const float scale = 0.17677669529663687f;
  const float* xb = x + (size_t)b * (NT * DIM);
  for (int i = tid; i < NT * DIM / 4; i += 256) {
    float4 v = ((const float4*)xb)[i];
    int e = i * 4, r = e / DIM, c = e - r * DIM;
    unsigned short* p = &xs[r][c];
    p[0] = f2bf(v.x); p[1] = f2bf(v.y); p[2] = f2bf(v.z); p[3] = f2bf(v.w);
  }
  __syncthreads();
  const int arow = (m0 + lc < NT) ? (m0 + lc) : (NT - 1);
  for (int h = 0; h < NH; ++h) {
    f32x4 acc[6];
#pragma unroll
    for (int t = 0; t < 6; ++t) acc[t] = (f32x4){0.f, 0.f, 0.f, 0.f};
#pragma unroll 2
    for (int kk = 0; kk < 12; ++kk) {
      short8 a = *(const short8*)&xs[arow][kk * 32 + g * 8];
#pragma unroll
      for (int t = 0; t < 6; ++t) {
        const int sel = t >> 1;
        const int wrow = sel * 384 + h * 32 + (t & 1) * 16 + lc;
        short8 bfr = *(const short8*)&Wq[wrow * 384 + kk * 32 + g * 8];
        acc[t] = __builtin_amdgcn_mfma_f32_16x16x32_bf16(a, bfr, acc[t], 0, 0, 0);
      }
    }
#pragma unroll
    for (int t = 0; t < 6; ++t) {
      const int sel = t >> 1;
      const int d = (t & 1) * 16 + lc;
      const float bias = qkv_b[sel * 384 + h * 32 + d];
#pragma unroll
      for (int r = 0; r < 4; ++r) {
        const int m = m0 + g * 4 + r;
        float v = acc[t][r] + bias;
        if (sel == 2) vT[d][m] = f2bf(v);
        else if (m < NT) {
          if (sel == 0) qs[m][d] = f2bf(v * scale);
          else ksm[m][d] = f2bf(v);
        }
      }
    }
    __syncthreads();
    f32x4 sac[4];
    {
      short8 a = *(const short8*)&qs[arow][g * 8];
#pragma unroll
      for (int t = 0; t < 4; ++t) {
        const int kr = (t * 16 + lc < NT) ? (t * 16 + lc) : (NT - 1);
        short8 bfr = *(const short8*)&ksm[kr][g * 8];
        sac[t] = __builtin_amdgcn_mfma_f32_16x16x32_bf16(
            a, bfr, (f32x4){0.f, 0.f, 0.f, 0.f}, 0, 0, 0);
      }
    }
    const float* bt = bias_tab + h * 4096;
    const float* mp = maskp + wi * 4096;
    float sv[4][4];
    float rmax[4];
#pragma unroll
    for (int r = 0; r < 4; ++r) rmax[r] = -3.0e38f;
#pragma unroll
    for (int t = 0; t < 4; ++t) {
      const int col = t * 16 + lc;
#pragma unroll
      for (int r = 0; r < 4; ++r) {
        const int row = m0 + g * 4 + r;
        float s2 = sac[t][r] + bt[row * 64 + col] + mp[row * 64 + col];
        sv[t][r] = s2;
        rmax[r] = fmaxf(rmax[r], s2);
      }
    }
#pragma unroll
    for (int r = 0; r < 4; ++r)
#pragma unroll
      for (int off = 1; off < 16; off <<= 1)
        rmax[r] = fmaxf(rmax[r], __shfl_xor(rmax[r], off));
    float rsum[4] = {0.f, 0.f, 0.f, 0.f};
#pragma unroll
    for (int t = 0; t < 4; ++t)
#pragma unroll
      for (int r = 0; r < 4; ++r) {
        float p = __expf(sv[t][r] - rmax[r]);
        sv[t][r] = p;
        rsum[r] += p;
      }
#pragma unroll
    for (int r = 0; r < 4; ++r) {
#pragma unroll
      for (int off = 1; off < 16; off <<= 1)
        rsum[r] += __shfl_xor(rsum[r], off);
      rsum[r] = 1.0f / rsum[r];
    }
#pragma unroll
    for (int t = 0; t < 4; ++t) {
      const int col = t * 16 + lc;
#pragma unroll
      for (int r = 0; r < 4; ++r) {
        const int row = m0 + g * 4 + r;
        if (row < NT) Ps[row][col] = f2bf(sv[t][r] * rsum[r]);
      }
    }
    __syncthreads();
    f32x4 oac[2];
    oac[0] = (f32x4){0.f, 0.f, 0.f, 0.f};
    oac[1] = (f32x4){0.f, 0.f, 0.f, 0.f};
#pragma unroll
    for (int k2 = 0; k2 < 2; ++k2) {
      short8 a = *(const short8*)&Ps[arow][k2 * 32 + g * 8];
#pragma unroll
      for (int tn = 0; tn < 2; ++tn) {
        short8 bfr = *(const short8*)&vT[tn * 16 + lc][k2 * 32 + g * 8];
        oac[tn] = __builtin_amdgcn_mfma_f32_16x16x32_bf16(a, bfr, oac[tn], 0, 0, 0);
      }
    }
    unsigned short* aob = AO + (size_t)b * (NT * DIM) + h * 32;
#pragma unroll
    for (int tn = 0; tn < 2; ++tn) {
      const int d = tn * 16 + lc;
#pragma unroll
      for (int r = 0; r < 4; ++r) {
        const int m = m0 + g * 4 + r;
        if (m < NT) aob[m * DIM + d] = f2bf(oac[tn][r]);
      }
    }
    __syncthreads();
  }
}

__global__ __launch_bounds__(256) void proj_kernel(
    const unsigned short* __restrict__ AO, const unsigned short* __restrict__ Wp,
    const float* __restrict__ proj_b, float* __restrict__ out, int lda) {
  __shared__ unsigned short As[128][72];
  __shared__ unsigned short Bs[128][72];
  const int s = blockIdx.x;
  const int xcd = s & 7, slot = s >> 3;
  const size_t m0 = (size_t)(xcd * 108 + slot / 3) * 128;
  const int n0 = (slot % 3) * 128;
  const int tid = threadIdx.x;
  const int wv = tid >> 6, ln = tid & 63, g = ln >> 4, lc = ln & 15;
  const int wr = (wv >> 1) * 64, wc = (wv & 1) * 64;
  f32x4 acc[4][4];
#pragma unroll
  for (int i = 0; i < 4; ++i)
#pragma unroll
    for (int j = 0; j < 4; ++j) acc[i][j] = (f32x4){0.f, 0.f, 0.f, 0.f};

  const int srow = tid >> 3, l8 = tid & 7;
  for (int kc = 0; kc < 6; ++kc) {
    const int k0 = kc * 64;
#pragma unroll
    for (int it = 0; it < 4; ++it) {
      const int r = srow + it * 32;
      *(short8*)&As[r][l8 * 8] =
          *(const short8*)&AO[(m0 + r) * (size_t)lda + k0 + l8 * 8];
      *(short8*)&Bs[r][l8 * 8] =
          *(const short8*)&Wp[(size_t)(n0 + r) * 384 + k0 + l8 * 8];
    }
    __syncthreads();
#pragma unroll
    for (int kk = 0; kk < 2; ++kk) {
      short8 af[4], bfr[4];
#pragma unroll
      for (int ms = 0; ms < 4; ++ms)
        af[ms] = *(const short8*)&As[wr + ms * 16 + lc][kk * 32 + g * 8];
#pragma unroll
      for (int ns = 0; ns < 4; ++ns)
        bfr[ns] = *(const short8*)&Bs[wc + ns * 16 + lc][kk * 32 + g * 8];
#pragma unroll
      for (int ms = 0; ms < 4; ++ms)
#pragma unroll
        for (int ns = 0; ns < 4; ++ns)
          acc[ms][ns] = __builtin_amdgcn_mfma_f32_16x16x32_bf16(
              af[ms], bfr[ns], acc[ms][ns], 0, 0, 0);
    }
    __syncthreads();
  }
#pragma unroll
  for (int ns = 0; ns < 4; ++ns) {
    const int n = n0 + wc + ns * 16 + lc;
    const float pb = proj_b[n];
#pragma unroll
    for (int ms = 0; ms < 4; ++ms)
#pragma unroll
      for (int rr = 0; rr < 4; ++rr) {
        const size_t m = m0 + wr + ms * 16 + g * 4 + rr;
        out[m * 384 + n] = acc[ms][ns][rr] + pb;
      }
  }
}

// -------------------------------------------------------------- launch ----
extern "C" void kernel_launch(void* const* d_in, const int* in_sizes, int n_in,
                              void* d_out, int out_size, void* d_ws, size_t ws_size,
                              hipStream_t stream) {
  const float* x      = (const float*)d_in[0];
  const float* mask   = (const float*)d_in[1];
  const float* qkv_w  = (const float*)d_in[2];
  const float* qkv_b  = (const float*)d_in[3];
  const float* proj_w = (const float*)d_in[4];
  const float* proj_b = (const float*)d_in[5];
  const float* rpb    = (const float*)d_in[6];
  const int*   rel    = (const int*)d_in[7];
  float* out = (float*)d_out;

  const size_t QKV_ELEMS = (size_t)3 * NH * HS;  // 127,401,984
  const size_t WQ_ELEMS = 1152 * 384, WP_ELEMS = 384 * 384;
  const size_t BMT_ELEMS = (size_t)NWIN * NH * 4096;
  const size_t need = (QKV_ELEMS + WQ_ELEMS + WP_ELEMS + BMT_ELEMS) * 2;

  if (ws_size >= need) {
    // -------- fast path: h-major Q/K planes + transposed V plane --------
    unsigned short* Qb  = (unsigned short*)d_ws;
    unsigned short* Kb  = Qb + NH * HS;
    unsigned short* VT  = Kb + NH * HS;            // [NH][32][MTOT]
    unsigned short* Wq  = VT + NH * HS;
    unsigned short* Wp  = Wq + WQ_ELEMS;
    unsigned short* bmt = Wp + WP_ELEMS;
    // xb (bf16 copy of x) lives in d_out (85 MB of 170 MB); dead before proj
    unsigned short* xb = (unsigned short*)d_out;

    convert_x<<<20736, 256, 0, stream>>>(x, xb);
    prep2_kernel<<<14592, 256, 0, stream>>>(qkv_w, proj_w, mask, rpb, rel,
                                            Wq, Wp, bmt);
    qkv_gemm5<<<7776, 256, 0, stream>>>(xb, Wq, qkv_b, Qb, Kb, VT);
    attn4_kernel<<<24576, 256, 0, stream>>>(Qb, Kb, VT, bmt);
    proj_hmajor<<<2592, 256, 0, stream>>>(Qb, Wp, proj_b, out);
  } else {
    // -------- fallback: round-1 fused path (88 MB scratch) --------
    unsigned short* Wq = (unsigned short*)d_ws;
    unsigned short* Wp = Wq + 442368;
    float* bias_tab = (float*)(Wp + 147456);
    float* maskp = bias_tab + 12 * 64 * 64;
    unsigned short* AO = (unsigned short*)(maskp + 64 * 64 * 64);
    prep_kernel<<<3520, 256, 0, stream>>>(qkv_w, proj_w, mask, rpb, rel,
                                          Wq, Wp, bias_tab, maskp);
    fused_attn<<<2048, 256, 0, stream>>>(x, Wq, qkv_b, bias_tab, maskp, AO);
    proj_kernel<<<2592, 256, 0, stream>>>(AO, Wp, proj_b, out, 384);
  }
}

// Round 15
// 432.043 us; speedup vs baseline: 1.0724x; 1.0434x over previous
//
#include <hip/hip_runtime.h>

#define DIM 384
#define NH 12
#define NT 54   // 49 window + 5 prompt tokens
#define NWIN 64
#define MTOT 110592             // 2048 * 54
#define HS ((size_t)MTOT * 32)  // per-head plane in h-major Q/K/V

typedef __attribute__((ext_vector_type(8))) short short8;
typedef __attribute__((ext_vector_type(4))) float f32x4;

__device__ __forceinline__ unsigned short f2bf(float f) {
  unsigned int u = __float_as_uint(f);
  u += 0x7fffu + ((u >> 16) & 1u);   // round-to-nearest-even
  return (unsigned short)(u >> 16);
}
__device__ __forceinline__ float bf2f(unsigned short s) {
  return __uint_as_float((unsigned int)s << 16);
}
// packed f32->bf16 (RTNE, same result as f2bf): D.lo=bf16(a), D.hi=bf16(b)
__device__ __forceinline__ unsigned int cvtpk(float a, float b) {
  unsigned int r;
  asm("v_cvt_pk_bf16_f32 %0, %1, %2" : "=v"(r) : "v"(a), "v"(b));
  return r;
}
__device__ __forceinline__ unsigned short cvt1(float a) {
  return (unsigned short)(cvtpk(a, a) & 0xffffu);
}
// async global->LDS, 16B per lane; LDS dest = wave-uniform base + lane*16
__device__ __forceinline__ void gload16(const unsigned short* g,
                                        unsigned short* l) {
  __builtin_amdgcn_global_load_lds(
      (const __attribute__((address_space(1))) void*)g,
      (__attribute__((address_space(3))) void*)l, 16, 0, 0);
}

// ===================================================== FAST PATH ==========
// convert_x: x fp32 -> bf16 into d_out (dead space until proj writes it)
__global__ __launch_bounds__(256) void convert_x(
    const float* __restrict__ x, unsigned short* __restrict__ xb) {
  const size_t i8 = ((size_t)blockIdx.x * 256 + threadIdx.x) * 8;
  float4 fa = *(const float4*)&x[i8];
  float4 fb = *(const float4*)&x[i8 + 4];
  uint4 u;
  u.x = cvtpk(fa.x, fa.y);
  u.y = cvtpk(fa.z, fa.w);
  u.z = cvtpk(fb.x, fb.y);
  u.w = cvtpk(fb.z, fb.w);
  *(uint4*)&xb[i8] = u;
}

// prep2: weights -> bf16; combined bias+mask table bmt in TRANSPOSED layout
// bmt[w][h][col][row] bf16: -1e30 in pad rows/cols, bias+mask elsewhere
__global__ __launch_bounds__(256) void prep2_kernel(
    const float* __restrict__ qkv_w, const float* __restrict__ proj_w,
    const float* __restrict__ mask, const float* __restrict__ rpb,
    const int* __restrict__ rel,
    unsigned short* __restrict__ Wq, unsigned short* __restrict__ Wp,
    unsigned short* __restrict__ bmt) {
  int idx = blockIdx.x * 256 + threadIdx.x;
  if (idx < 1152 * 384) { Wq[idx] = f2bf(qkv_w[idx]); return; }
  idx -= 1152 * 384;
  if (idx < 384 * 384) { Wp[idx] = f2bf(proj_w[idx]); return; }
  idx -= 384 * 384;
  if (idx < NWIN * NH * 64 * 64) {
    int w = idx / (NH * 4096);
    int rem = idx - w * (NH * 4096);
    int h = rem >> 12, r = (rem >> 6) & 63, c = rem & 63;
    float v;
    if (r >= NT || c >= NT) v = -1e30f;
    else if (r >= 5 && c >= 5)
      v = rpb[rel[(r - 5) * 49 + (c - 5)] * NH + h] +
          mask[w * 2401 + (r - 5) * 49 + (c - 5)];
    else v = 0.0f;
    // transposed store: [w][h][c][r]
    bmt[w * (NH * 4096) + (h << 12) + (c << 6) + r] = f2bf(v);
  }
}

// QKV GEMM v8: R10-proven gload_lds + XOR swizzle main loop, plus
// EPILOGUE-VIA-LDS: accumulator transposed through the (reused) 32 KB
// staging buffer as a chunk-swizzled [128][128] tile, then stored as
// fully-coalesced 64B-per-head runs (8 stores/thread vs 64 2B scatters).
// grid = 7776 = 8 xcd * 108 m * 9 n.  C[m][n] = xb[m][k]*Wq[n][k]+b[n]
__global__ __launch_bounds__(256) void qkv_gemm7(
    const unsigned short* __restrict__ xb, const unsigned short* __restrict__ Wq,
    const float* __restrict__ qkv_b,
    unsigned short* __restrict__ Qb, unsigned short* __restrict__ Kb,
    unsigned short* __restrict__ Vb) {
  __shared__ unsigned short LDS[2][128][64];   // staging A/B; reused for out
  unsigned short (*As)[64] = LDS[0];
  unsigned short (*Bs)[64] = LDS[1];
  const int s = blockIdx.x;
  const int xcd = s & 7, slot = s >> 3;
  const size_t m0 = (size_t)(xcd * 108 + slot / 9) * 128;
  const int n0 = (slot % 9) * 128;
  const int tid = threadIdx.x;
  const int wv = tid >> 6, ln = tid & 63, g = ln >> 4, lc = ln & 15;
  const int wr = (wv >> 1) * 64, wc = (wv & 1) * 64;
  const int l7 = lc & 7;
  const int lr8 = ln >> 3;                       // row-in-8 for staging
  const int sc8 = (((ln & 7) ^ lr8) & 7) * 8;    // swizzled source chunk (elems)

  f32x4 acc[4][4];
#pragma unroll
  for (int i = 0; i < 4; ++i)
#pragma unroll
    for (int j = 0; j < 4; ++j) acc[i][j] = (f32x4){0.f, 0.f, 0.f, 0.f};

#pragma unroll
  for (int kc = 0; kc < 6; ++kc) {
    const int k0 = kc * 64;
    if (kc) __syncthreads();          // all waves done reading prev tile
#pragma unroll
    for (int it = 0; it < 4; ++it) {  // wave stages rows wv*32 .. wv*32+31
      const int r0 = wv * 32 + it * 8;
      const int r = r0 + lr8;
      gload16(&xb[(m0 + r) * 384 + k0 + sc8], &As[r0][0]);
      gload16(&Wq[(size_t)(n0 + r) * 384 + k0 + sc8], &Bs[r0][0]);
    }
    __syncthreads();                  // drains vmcnt(0) -> tile visible
#pragma unroll
    for (int kk = 0; kk < 2; ++kk) {
      const int cix = (((kk * 4 + g) ^ l7)) * 8;   // swizzled read chunk
      short8 af[4], bfv[4];
#pragma unroll
      for (int ms = 0; ms < 4; ++ms)
        af[ms] = *(const short8*)&As[wr + ms * 16 + lc][cix];
#pragma unroll
      for (int ns = 0; ns < 4; ++ns)
        bfv[ns] = *(const short8*)&Bs[wc + ns * 16 + lc][cix];
#pragma unroll
      for (int ms = 0; ms < 4; ++ms)
#pragma unroll
        for (int ns = 0; ns < 4; ++ns)
          acc[ms][ns] = __builtin_amdgcn_mfma_f32_16x16x32_bf16(
              af[ms], bfv[ns], acc[ms][ns], 0, 0, 0);
    }
  }

  // ---- epilogue: acc -> swizzled LDS [128][128] -> coalesced stores ----
  __syncthreads();                     // staging reads all done; reuse LDS
  unsigned short* F = &LDS[0][0][0];   // flat [128 rows][16 chunks of 8]
  const int sel = n0 / 384;            // 384 = 3*128, no crossing
  const float factor = (sel == 0) ? 0.17677669529663687f : 1.0f;
#pragma unroll
  for (int ns = 0; ns < 4; ++ns) {
    const int c = wc + ns * 16 + lc;
    const int ccol = c >> 3, ce = c & 7;
    const float bias = qkv_b[n0 + c];
#pragma unroll
    for (int ms = 0; ms < 4; ++ms) {
      const int rbase = wr + ms * 16 + g * 4;
#pragma unroll
      for (int rr = 0; rr < 4; ++rr) {
        const int r = rbase + rr;
        F[r * 128 + (((ccol ^ (r & 7)) << 3) | ce)] =
            cvt1((acc[ms][ns][rr] + bias) * factor);
      }
    }
  }
  __syncthreads();
  unsigned short* outp = (sel == 0) ? Qb : (sel == 1 ? Kb : Vb);
  const int hh = tid >> 6;                       // head within block (0..3)
  const int seg = tid & 63;
  unsigned short* hp = outp + (size_t)(((n0 - sel * 384) >> 5) + hh) * HS;
#pragma unroll
  for (int rep = 0; rep < 2; ++rep) {
    const int m = seg + rep * 64;
    short8 t0, t1, t2, t3;
    t0 = *(const short8*)&F[m * 128 + ((hh * 4 + 0) ^ (m & 7)) * 8];
    t1 = *(const short8*)&F[m * 128 + ((hh * 4 + 1) ^ (m & 7)) * 8];
    t2 = *(const short8*)&F[m * 128 + ((hh * 4 + 2) ^ (m & 7)) * 8];
    t3 = *(const short8*)&F[m * 128 + ((hh * 4 + 3) ^ (m & 7)) * 8];
    unsigned short* dst = &hp[(m0 + m) * 32];
    *(short8*)&dst[0]  = t0;
    *(short8*)&dst[8]  = t1;
    *(short8*)&dst[16] = t2;
    *(short8*)&dst[24] = t3;
  }
}

// attention (R11-proven attn2): w-locality XCD mapping; hoisted K/bias loads;
// shuffle softmax. grid = 24576 = 8 xcd * (8 wl * 32 batch * 12 h)
__global__ __launch_bounds__(256) void attn2_kernel(
    unsigned short* __restrict__ Qb, const unsigned short* __restrict__ Kb,
    const unsigned short* __restrict__ Vb, const unsigned short* __restrict__ bmt) {
  __shared__ unsigned short Ps[NT][72];
  __shared__ unsigned short vT[32][72];
  const int s = blockIdx.x;
  const int xcd = s & 7, r3 = s >> 3;       // r3 in [0,3072)
  const int h = r3 % 12;
  const int t2 = r3 / 12;                    // [0,256)
  const int batch = t2 & 31;
  const int w = xcd * 8 + (t2 >> 5);         // this XCD's 8 windows
  const int b = batch * 64 + w;
  const int tid = threadIdx.x;
  const int wv = tid >> 6, ln = tid & 63, g = ln >> 4, lc = ln & 15;
  const int m0 = wv * 16;
  const size_t base = (size_t)b * NT;
  const int arow = (m0 + lc < NT) ? (m0 + lc) : (NT - 1);
  unsigned short* Qh = Qb + (size_t)h * HS;
  const unsigned short* Kh = Kb + (size_t)h * HS;
  const unsigned short* Vh = Vb + (size_t)h * HS;

  // zero vT pad cols m=54..63 (P=0 there; keep product finite); 320 > 256
  for (int i = tid; i < 320; i += 256) {
    int d = i / 10, m = NT + (i - d * 10);
    vT[d][m] = 0;
  }

  // ---- issue ALL global loads up front (10 independent loads in flight) ----
  const int vr = tid >> 2, vc = (tid & 3) * 8;
  short8 vv;
  if (tid < 216)
    vv = *(const short8*)&Vh[(base + vr) * 32 + vc];

  short8 a = *(const short8*)&Qh[(base + arow) * 32 + g * 8];
  const unsigned short* bmh = &bmt[(size_t)(w * NH + h) << 12];  // [c][r]
  const int row0 = m0 + g * 4;
  short8 kb[4];
  uint2 uu[4];
#pragma unroll
  for (int t = 0; t < 4; ++t) {
    const int col = t * 16 + lc;
    const int kr = (col < NT) ? col : (NT - 1);
    kb[t] = *(const short8*)&Kh[(base + kr) * 32 + g * 8];
    uu[t] = *(const uint2*)&bmh[(col << 6) + row0];  // 4 bf16 rows r0..r0+3
  }

  // ---- S = q@k^T with C initialized from transposed bias+mask table ----
  f32x4 sac[4];
#pragma unroll
  for (int t = 0; t < 4; ++t) {
    f32x4 c0;
    c0[0] = bf2f((unsigned short)(uu[t].x & 0xffffu));
    c0[1] = bf2f((unsigned short)(uu[t].x >> 16));
    c0[2] = bf2f((unsigned short)(uu[t].y & 0xffffu));
    c0[3] = bf2f((unsigned short)(uu[t].y >> 16));
    sac[t] = __builtin_amdgcn_mfma_f32_16x16x32_bf16(a, kb[t], c0, 0, 0, 0);
  }
  // ---- row softmax (16-lane groups own rows) ----
  float rmax[4] = {-3.0e38f, -3.0e38f, -3.0e38f, -3.0e38f};
#pragma unroll
  for (int t = 0; t < 4; ++t)
#pragma unroll
    for (int rr = 0; rr < 4; ++rr) rmax[rr] = fmaxf(rmax[rr], sac[t][rr]);
#pragma unroll
  for (int rr = 0; rr < 4; ++rr)
#pragma unroll
    for (int off = 1; off < 16; off <<= 1)
      rmax[rr] = fmaxf(rmax[rr], __shfl_xor(rmax[rr], off));
  float rsum[4] = {0.f, 0.f, 0.f, 0.f};
#pragma unroll
  for (int t = 0; t < 4; ++t)
#pragma unroll
    for (int rr = 0; rr < 4; ++rr) {
      float p = __expf(sac[t][rr] - rmax[rr]);
      sac[t][rr] = p;
      rsum[rr] += p;
    }
#pragma unroll
  for (int rr = 0; rr < 4; ++rr) {
#pragma unroll
    for (int off = 1; off < 16; off <<= 1)
      rsum[rr] += __shfl_xor(rsum[rr], off);
    rsum[rr] = 1.0f / rsum[rr];
  }
#pragma unroll
  for (int t = 0; t < 4; ++t) {
    const int col = t * 16 + lc;
    const unsigned int u01 = cvtpk(sac[t][0] * rsum[0], sac[t][1] * rsum[1]);
    const unsigned int u23 = cvtpk(sac[t][2] * rsum[2], sac[t][3] * rsum[3]);
    if (row0 < NT)     Ps[row0][col]     = (unsigned short)(u01 & 0xffffu);
    if (row0 + 1 < NT) Ps[row0 + 1][col] = (unsigned short)(u01 >> 16);
    if (row0 + 2 < NT) Ps[row0 + 2][col] = (unsigned short)(u23 & 0xffffu);
    if (row0 + 3 < NT) Ps[row0 + 3][col] = (unsigned short)(u23 >> 16);
  }
  // ---- v transpose into LDS ----
  if (tid < 216) {
#pragma unroll
    for (int j = 0; j < 8; ++j) vT[vc + j][vr] = (unsigned short)vv[j];
  }
  __syncthreads();
  // ---- O = P @ V ----
  f32x4 oac[2];
  oac[0] = (f32x4){0.f, 0.f, 0.f, 0.f};
  oac[1] = (f32x4){0.f, 0.f, 0.f, 0.f};
#pragma unroll
  for (int k2 = 0; k2 < 2; ++k2) {
    short8 pa = *(const short8*)&Ps[arow][k2 * 32 + g * 8];
#pragma unroll
    for (int tn = 0; tn < 2; ++tn) {
      short8 vb = *(const short8*)&vT[tn * 16 + lc][k2 * 32 + g * 8];
      oac[tn] = __builtin_amdgcn_mfma_f32_16x16x32_bf16(pa, vb, oac[tn], 0, 0, 0);
    }
  }
  // write O over this block's own Q slab (q is dead after QK^T)
#pragma unroll
  for (int tn = 0; tn < 2; ++tn) {
    const int d = tn * 16 + lc;
    const unsigned int u01 = cvtpk(oac[tn][0], oac[tn][1]);
    const unsigned int u23 = cvtpk(oac[tn][2], oac[tn][3]);
    unsigned short* p = &Qh[(base + row0) * 32 + d];
    if (row0 < NT)     p[0]  = (unsigned short)(u01 & 0xffffu);
    if (row0 + 1 < NT) p[32] = (unsigned short)(u01 >> 16);
    if (row0 + 2 < NT) p[64] = (unsigned short)(u23 & 0xffffu);
    if (row0 + 3 < NT) p[96] = (unsigned short)(u23 >> 16);
  }
}

// proj GEMM over h-major A (the O planes) — R6-proven reg-staged 2-barrier.
// out[m][n]=sum_k A[m][k]*Wp[n][k]+b;  A[m][h*32+d] = AO[h*HS + m*32 + d]
// grid = 2592 = 8 xcd * 108 m * 3 n
__global__ __launch_bounds__(256) void proj_hmajor(
    const unsigned short* __restrict__ AO, const unsigned short* __restrict__ Wp,
    const float* __restrict__ proj_b, float* __restrict__ out) {
  __shared__ unsigned short As[128][72];
  __shared__ unsigned short Bs[128][72];
  const int s = blockIdx.x;
  const int xcd = s & 7, slot = s >> 3;
  const size_t m0 = (size_t)(xcd * 108 + slot / 3) * 128;
  const int n0 = (slot % 3) * 128;
  const int tid = threadIdx.x;
  const int wv = tid >> 6, ln = tid & 63, g = ln >> 4, lc = ln & 15;
  const int wr = (wv >> 1) * 64, wc = (wv & 1) * 64;
  f32x4 acc[4][4];
#pragma unroll
  for (int i = 0; i < 4; ++i)
#pragma unroll
    for (int j = 0; j < 4; ++j) acc[i][j] = (f32x4){0.f, 0.f, 0.f, 0.f};

  const int srow = tid >> 3, l8 = tid & 7;
  for (int kc = 0; kc < 6; ++kc) {
    const int k0 = kc * 64;
    const int kg = k0 + l8 * 8;
    const int hh = kg >> 5, dd = kg & 31;         // 8-chunk stays in one head
#pragma unroll
    for (int it = 0; it < 4; ++it) {
      const int r = srow + it * 32;
      *(short8*)&As[r][l8 * 8] =
          *(const short8*)&AO[(size_t)hh * HS + (m0 + r) * 32 + dd];
      *(short8*)&Bs[r][l8 * 8] =
          *(const short8*)&Wp[(size_t)(n0 + r) * 384 + kg];
    }
    __syncthreads();
#pragma unroll
    for (int kk = 0; kk < 2; ++kk) {
      short8 af[4], bfv[4];
#pragma unroll
      for (int ms = 0; ms < 4; ++ms)
        af[ms] = *(const short8*)&As[wr + ms * 16 + lc][kk * 32 + g * 8];
#pragma unroll
      for (int ns = 0; ns < 4; ++ns)
        bfv[ns] = *(const short8*)&Bs[wc + ns * 16 + lc][kk * 32 + g * 8];
#pragma unroll
      for (int ms = 0; ms < 4; ++ms)
#pragma unroll
        for (int ns = 0; ns < 4; ++ns)
          acc[ms][ns] = __builtin_amdgcn_mfma_f32_16x16x32_bf16(
              af[ms], bfv[ns], acc[ms][ns], 0, 0, 0);
    }
    __syncthreads();
  }
#pragma unroll
  for (int ns = 0; ns < 4; ++ns) {
    const int n = n0 + wc + ns * 16 + lc;
    const float pb = proj_b[n];
#pragma unroll
    for (int ms = 0; ms < 4; ++ms)
#pragma unroll
      for (int rr = 0; rr < 4; ++rr) {
        const size_t m = m0 + wr + ms * 16 + g * 4 + rr;
        out[m * 384 + n] = acc[ms][ns][rr] + pb;
      }
  }
}

// ================================================= FALLBACK (round-1) =====
__global__ __launch_bounds__(256) void prep_kernel(
    const float* __restrict__ qkv_w, const float* __restrict__ proj_w,
    const float* __restrict__ mask, const float* __restrict__ rpb,
    const int* __restrict__ rel,
    unsigned short* __restrict__ Wq, unsigned short* __restrict__ Wp,
    float* __restrict__ bias_tab, float* __restrict__ maskp) {
  int idx = blockIdx.x * 256 + threadIdx.x;
  if (idx < 1152 * 384) { Wq[idx] = f2bf(qkv_w[idx]); return; }
  idx -= 1152 * 384;
  if (idx < 384 * 384) { Wp[idx] = f2bf(proj_w[idx]); return; }
  idx -= 384 * 384;
  if (idx < NH * 64 * 64) {
    int h = idx >> 12, r = (idx >> 6) & 63, c = idx & 63;
    float v;
    if (r >= NT || c >= NT) v = -1e30f;
    else if (r >= 5 && c >= 5) v = rpb[rel[(r - 5) * 49 + (c - 5)] * NH + h];
    else v = 0.0f;
    bias_tab[idx] = v;
    return;
  }
  idx -= NH * 64 * 64;
  if (idx < NWIN * 64 * 64) {
    int w = idx >> 12, r = (idx >> 6) & 63, c = idx & 63;
    float v = 0.0f;
    if (r >= 5 && r < NT && c >= 5 && c < NT)
      v = mask[w * 2401 + (r - 5) * 49 + (c - 5)];
    maskp[idx] = v;
  }
}

__global__ __launch_bounds__(256) void fused_attn(
    const float* __restrict__ x, const unsigned short* __restrict__ Wq,
    const float* __restrict__ qkv_b, const float* __restrict__ bias_tab,
    const float* __restrict__ maskp, unsigned short* __restrict__ AO) {
  __shared__ unsigned short xs[NT][392];
  __shared__ unsigned short qs[NT][40];
  __shared__ unsigned short ksm[NT][40];
  __shared__ unsigned short vT[32][72];
  __shared__ unsigned short Ps[NT][72];
  const int b = blockIdx.x;
  const int tid = threadIdx.x;
  const int wv = tid >> 6, ln = tid & 63;
  const int g = ln >> 4, lc = ln & 15;
  const int m0 = wv * 16;
  const int wi = b & 63;
  const float scale = 0.17677669529663687f;
  const float* xb = x + (size_t)b * (NT * DIM);
  for (int i = tid; i < NT * DIM / 4; i += 256) {
    float4 v = ((const float4*)xb)[i];
    int e = i * 4, r = e / DIM, c = e - r * DIM;
    unsigned short* p = &xs[r][c];
    p[0] = f2bf(v.x); p[1] = f2bf(v.y); p[2] = f2bf(v.z); p[3] = f2bf(v.w);
  }
  __syncthreads();
  const int arow = (m0 + lc < NT) ? (m0 + lc) : (NT - 1);
  for (int h = 0; h < NH; ++h) {
    f32x4 acc[6];
#pragma unroll
    for (int t = 0; t < 6; ++t) acc[t] = (f32x4){0.f, 0.f, 0.f, 0.f};
#pragma unroll 2
    for (int kk = 0; kk < 12; ++kk) {
      short8 a = *(const short8*)&xs[arow][kk * 32 + g * 8];
#pragma unroll
      for (int t = 0; t < 6; ++t) {
        const int sel = t >> 1;
        const int wrow = sel * 384 + h * 32 + (t & 1) * 16 + lc;
        short8 bfr = *(const short8*)&Wq[wrow * 384 + kk * 32 + g * 8];
        acc[t] = __builtin_amdgcn_mfma_f32_16x16x32_bf16(a, bfr, acc[t], 0, 0, 0);
      }
    }
#pragma unroll
    for (int t = 0; t < 6; ++t) {
      const int sel = t >> 1;
      const int d = (t & 1) * 16 + lc;
      const float bias = qkv_b[sel * 384 + h * 32 + d];
#pragma unroll
      for (int r = 0; r < 4; ++r) {
        const int m = m0 + g * 4 + r;
        float v = acc[t][r] + bias;
        if (sel == 2) vT[d][m] = f2bf(v);
        else if (m < NT) {
          if (sel == 0) qs[m][d] = f2bf(v * scale);
          else ksm[m][d] = f2bf(v);
        }
      }
    }
    __syncthreads();
    f32x4 sac[4];
    {
      short8 a = *(const short8*)&qs[arow][g * 8];
#pragma unroll
      for (int t = 0; t < 4; ++t) {
        const int kr = (t * 16 + lc < NT) ? (t * 16 + lc) : (NT - 1);
        short8 bfr = *(const short8*)&ksm[kr][g * 8];
        sac[t] = __builtin_amdgcn_mfma_f32_16x16x32_bf16(
            a, bfr, (f32x4){0.f, 0.f, 0.f, 0.f}, 0, 0, 0);
      }
    }
    const float* bt = bias_tab + h * 4096;
    const float* mp = maskp + wi * 4096;
    float sv[4][4];
    float rmax[4];
#pragma unroll
    for (int r = 0; r < 4; ++r) rmax[r] = -3.0e38f;
#pragma unroll
    for (int t = 0; t < 4; ++t) {
      const int col = t * 16 + lc;
#pragma unroll
      for (int r = 0; r < 4; ++r) {
        const int row = m0 + g * 4 + r;
        float s2 = sac[t][r] + bt[row * 64 + col] + mp[row * 64 + col];
        sv[t][r] = s2;
        rmax[r] = fmaxf(rmax[r], s2);
      }
    }
#pragma unroll
    for (int r = 0; r < 4; ++r)
#pragma unroll
      for (int off = 1; off < 16; off <<= 1)
        rmax[r] = fmaxf(rmax[r], __shfl_xor(rmax[r], off));
    float rsum[4] = {0.f, 0.f, 0.f, 0.f};
#pragma unroll
    for (int t = 0; t < 4; ++t)
#pragma unroll
      for (int r = 0; r < 4; ++r) {
        float p = __expf(sv[t][r] - rmax[r]);
        sv[t][r] = p;
        rsum[r] += p;
      }
#pragma unroll
    for (int r = 0; r < 4; ++r) {
#pragma unroll
      for (int off = 1; off < 16; off <<= 1)
        rsum[r] += __shfl_xor(rsum[r], off);
      rsum[r] = 1.0f / rsum[r];
    }
#pragma unroll
    for (int t = 0; t < 4; ++t) {
      const int col = t * 16 + lc;
#pragma unroll
      for (int r = 0; r < 4; ++r) {
        const int row = m0 + g * 4 + r;
        if (row < NT) Ps[row][col] = f2bf(sv[t][r] * rsum[r]);
      }
    }
    __syncthreads();
    f32x4 oac[2];
    oac[0] = (f32x4){0.f, 0.f, 0.f, 0.f};
    oac[1] = (f32x4){0.f, 0.f, 0.f, 0.f};
#pragma unroll
    for (int k2 = 0; k2 < 2; ++k2) {
      short8 a = *(const short8*)&Ps[arow][k2 * 32 + g * 8];
#pragma unroll
      for (int tn = 0; tn < 2; ++tn) {
        short8 bfr = *(const short8*)&vT[tn * 16 + lc][k2 * 32 + g * 8];
        oac[tn] = __builtin_amdgcn_mfma_f32_16x16x32_bf16(a, bfr, oac[tn], 0, 0, 0);
      }
    }
    unsigned short* aob = AO + (size_t)b * (NT * DIM) + h * 32;
#pragma unroll
    for (int tn = 0; tn < 2; ++tn) {
      const int d = tn * 16 + lc;
#pragma unroll
      for (int r = 0; r < 4; ++r) {
        const int m = m0 + g * 4 + r;
        if (m < NT) aob[m * DIM + d] = f2bf(oac[tn][r]);
      }
    }
    __syncthreads();
  }
}

__global__ __launch_bounds__(256) void proj_kernel(
    const unsigned short* __restrict__ AO, const unsigned short* __restrict__ Wp,
    const float* __restrict__ proj_b, float* __restrict__ out, int lda) {
  __shared__ unsigned short As[128][72];
  __shared__ unsigned short Bs[128][72];
  const int s = blockIdx.x;
  const int xcd = s & 7, slot = s >> 3;
  const size_t m0 = (size_t)(xcd * 108 + slot / 3) * 128;
  const int n0 = (slot % 3) * 128;
  const int tid = threadIdx.x;
  const int wv = tid >> 6, ln = tid & 63, g = ln >> 4, lc = ln & 15;
  const int wr = (wv >> 1) * 64, wc = (wv & 1) * 64;
  f32x4 acc[4][4];
#pragma unroll
  for (int i = 0; i < 4; ++i)
#pragma unroll
    for (int j = 0; j < 4; ++j) acc[i][j] = (f32x4){0.f, 0.f, 0.f, 0.f};

  const int srow = tid >> 3, l8 = tid & 7;
  for (int kc = 0; kc < 6; ++kc) {
    const int k0 = kc * 64;
#pragma unroll
    for (int it = 0; it < 4; ++it) {
      const int r = srow + it * 32;
      *(short8*)&As[r][l8 * 8] =
          *(const short8*)&AO[(m0 + r) * (size_t)lda + k0 + l8 * 8];
      *(short8*)&Bs[r][l8 * 8] =
          *(const short8*)&Wp[(size_t)(n0 + r) * 384 + k0 + l8 * 8];
    }
    __syncthreads();
#pragma unroll
    for (int kk = 0; kk < 2; ++kk) {
      short8 af[4], bfr[4];
#pragma unroll
      for (int ms = 0; ms < 4; ++ms)
        af[ms] = *(const short8*)&As[wr + ms * 16 + lc][kk * 32 + g * 8];
#pragma unroll
      for (int ns = 0; ns < 4; ++ns)
        bfr[ns] = *(const short8*)&Bs[wc + ns * 16 + lc][kk * 32 + g * 8];
#pragma unroll
      for (int ms = 0; ms < 4; ++ms)
#pragma unroll
        for (int ns = 0; ns < 4; ++ns)
          acc[ms][ns] = __builtin_amdgcn_mfma_f32_16x16x32_bf16(
              af[ms], bfr[ns], acc[ms][ns], 0, 0, 0);
    }
    __syncthreads();
  }
#pragma unroll
  for (int ns = 0; ns < 4; ++ns) {
    const int n = n0 + wc + ns * 16 + lc;
    const float pb = proj_b[n];
#pragma unroll
    for (int ms = 0; ms < 4; ++ms)
#pragma unroll
      for (int rr = 0; rr < 4; ++rr) {
        const size_t m = m0 + wr + ms * 16 + g * 4 + rr;
        out[m * 384 + n] = acc[ms][ns][rr] + pb;
      }
  }
}

// -------------------------------------------------------------- launch ----
extern "C" void kernel_launch(void* const* d_in, const int* in_sizes, int n_in,
                              void* d_out, int out_size, void* d_ws, size_t ws_size,
                              hipStream_t stream) {
  const float* x      = (const float*)d_in[0];
  const float* mask   = (const float*)d_in[1];
  const float* qkv_w  = (const float*)d_in[2];
  const float* qkv_b  = (const float*)d_in[3];
  const float* proj_w = (const float*)d_in[4];
  const float* proj_b = (const float*)d_in[5];
  const float* rpb    = (const float*)d_in[6];
  const int*   rel    = (const int*)d_in[7];
  float* out = (float*)d_out;

  const size_t QKV_ELEMS = (size_t)3 * NH * HS;  // 127,401,984
  const size_t WQ_ELEMS = 1152 * 384, WP_ELEMS = 384 * 384;
  const size_t BMT_ELEMS = (size_t)NWIN * NH * 4096;
  const size_t need = (QKV_ELEMS + WQ_ELEMS + WP_ELEMS + BMT_ELEMS) * 2;

  if (ws_size >= need) {
    // -------- fast path: h-major Q/K/V planes --------
    unsigned short* Qb  = (unsigned short*)d_ws;
    unsigned short* Kb  = Qb + NH * HS;
    unsigned short* Vb  = Kb + NH * HS;
    unsigned short* Wq  = Vb + NH * HS;
    unsigned short* Wp  = Wq + WQ_ELEMS;
    unsigned short* bmt = Wp + WP_ELEMS;
    // xb (bf16 copy of x) lives in d_out (85 MB of 170 MB); dead before proj
    unsigned short* xb = (unsigned short*)d_out;

    convert_x<<<20736, 256, 0, stream>>>(x, xb);
    prep2_kernel<<<14592, 256, 0, stream>>>(qkv_w, proj_w, mask, rpb, rel,
                                            Wq, Wp, bmt);
    qkv_gemm7<<<7776, 256, 0, stream>>>(xb, Wq, qkv_b, Qb, Kb, Vb);
    attn2_kernel<<<24576, 256, 0, stream>>>(Qb, Kb, Vb, bmt);
    proj_hmajor<<<2592, 256, 0, stream>>>(Qb, Wp, proj_b, out);
  } else {
    // -------- fallback: round-1 fused path (88 MB scratch) --------
    unsigned short* Wq = (unsigned short*)d_ws;
    unsigned short* Wp = Wq + 442368;
    float* bias_tab = (float*)(Wp + 147456);
    float* maskp = bias_tab + 12 * 64 * 64;
    unsigned short* AO = (unsigned short*)(maskp + 64 * 64 * 64);
    prep_kernel<<<3520, 256, 0, stream>>>(qkv_w, proj_w, mask, rpb, rel,
                                          Wq, Wp, bias_tab, maskp);
    fused_attn<<<2048, 256, 0, stream>>>(x, Wq, qkv_b, bias_tab, maskp, AO);
    proj_kernel<<<2592, 256, 0, stream>>>(AO, Wp, proj_b, out, 384);
  }
}

// Round 16
// 396.607 us; speedup vs baseline: 1.1682x; 1.0893x over previous
//
#include <hip/hip_runtime.h>

#define DIM 384
#define NH 12
#define NT 54   // 49 window + 5 prompt tokens
#define NWIN 64
#define MTOT 110592             // 2048 * 54
#define HS ((size_t)MTOT * 32)  // per-head plane in h-major Q/K/V

typedef __attribute__((ext_vector_type(8))) short short8;
typedef __attribute__((ext_vector_type(4))) float f32x4;

__device__ __forceinline__ unsigned short f2bf(float f) {
  unsigned int u = __float_as_uint(f);
  u += 0x7fffu + ((u >> 16) & 1u);   // round-to-nearest-even
  return (unsigned short)(u >> 16);
}
__device__ __forceinline__ float bf2f(unsigned short s) {
  return __uint_as_float((unsigned int)s << 16);
}
// packed f32->bf16 (RTNE, same result as f2bf): D.lo=bf16(a), D.hi=bf16(b)
__device__ __forceinline__ unsigned int cvtpk(float a, float b) {
  unsigned int r;
  asm("v_cvt_pk_bf16_f32 %0, %1, %2" : "=v"(r) : "v"(a), "v"(b));
  return r;
}
// async global->LDS, 16B per lane; LDS dest = wave-uniform base + lane*16
__device__ __forceinline__ void gload16(const unsigned short* g,
                                        unsigned short* l) {
  __builtin_amdgcn_global_load_lds(
      (const __attribute__((address_space(1))) void*)g,
      (__attribute__((address_space(3))) void*)l, 16, 0, 0);
}

// ===================================================== FAST PATH ==========
// convert_x: x fp32 -> bf16 into d_out (dead space until proj writes it)
__global__ __launch_bounds__(256) void convert_x(
    const float* __restrict__ x, unsigned short* __restrict__ xb) {
  const size_t i8 = ((size_t)blockIdx.x * 256 + threadIdx.x) * 8;
  float4 fa = *(const float4*)&x[i8];
  float4 fb = *(const float4*)&x[i8 + 4];
  uint4 u;
  u.x = cvtpk(fa.x, fa.y);
  u.y = cvtpk(fa.z, fa.w);
  u.z = cvtpk(fb.x, fb.y);
  u.w = cvtpk(fb.z, fb.w);
  *(uint4*)&xb[i8] = u;
}

// prep2: weights -> bf16; combined bias+mask table bmt in TRANSPOSED layout
// bmt[w][h][col][row] bf16: -1e30 in pad rows/cols, bias+mask elsewhere
__global__ __launch_bounds__(256) void prep2_kernel(
    const float* __restrict__ qkv_w, const float* __restrict__ proj_w,
    const float* __restrict__ mask, const float* __restrict__ rpb,
    const int* __restrict__ rel,
    unsigned short* __restrict__ Wq, unsigned short* __restrict__ Wp,
    unsigned short* __restrict__ bmt) {
  int idx = blockIdx.x * 256 + threadIdx.x;
  if (idx < 1152 * 384) { Wq[idx] = f2bf(qkv_w[idx]); return; }
  idx -= 1152 * 384;
  if (idx < 384 * 384) { Wp[idx] = f2bf(proj_w[idx]); return; }
  idx -= 384 * 384;
  if (idx < NWIN * NH * 64 * 64) {
    int w = idx / (NH * 4096);
    int rem = idx - w * (NH * 4096);
    int h = rem >> 12, r = (rem >> 6) & 63, c = rem & 63;
    float v;
    if (r >= NT || c >= NT) v = -1e30f;
    else if (r >= 5 && c >= 5)
      v = rpb[rel[(r - 5) * 49 + (c - 5)] * NH + h] +
          mask[w * 2401 + (r - 5) * 49 + (c - 5)];
    else v = 0.0f;
    // transposed store: [w][h][c][r]
    bmt[w * (NH * 4096) + (h << 12) + (c << 6) + r] = f2bf(v);
  }
}

// QKV GEMM (R10/R11-proven): gload_lds w16 staging into UNPADDED [128][64]
// tiles with XOR chunk-swizzle; 2-barrier loop; scatter epilogue.
// grid = 7776 = 8 xcd * 108 m * 9 n.  C[m][n] = xb[m][k]*Wq[n][k]+b[n]
__global__ __launch_bounds__(256) void qkv_gemm5(
    const unsigned short* __restrict__ xb, const unsigned short* __restrict__ Wq,
    const float* __restrict__ qkv_b,
    unsigned short* __restrict__ Qb, unsigned short* __restrict__ Kb,
    unsigned short* __restrict__ Vb) {
  __shared__ unsigned short As[128][64];
  __shared__ unsigned short Bs[128][64];
  const int s = blockIdx.x;
  const int xcd = s & 7, slot = s >> 3;
  const size_t m0 = (size_t)(xcd * 108 + slot / 9) * 128;
  const int n0 = (slot % 9) * 128;
  const int tid = threadIdx.x;
  const int wv = tid >> 6, ln = tid & 63, g = ln >> 4, lc = ln & 15;
  const int wr = (wv >> 1) * 64, wc = (wv & 1) * 64;
  const int l7 = lc & 7;
  const int lr8 = ln >> 3;                       // row-in-8 for staging
  const int sc8 = (((ln & 7) ^ lr8) & 7) * 8;    // swizzled source chunk (elems)

  f32x4 acc[4][4];
#pragma unroll
  for (int i = 0; i < 4; ++i)
#pragma unroll
    for (int j = 0; j < 4; ++j) acc[i][j] = (f32x4){0.f, 0.f, 0.f, 0.f};

#pragma unroll
  for (int kc = 0; kc < 6; ++kc) {
    const int k0 = kc * 64;
    if (kc) __syncthreads();          // all waves done reading prev tile
#pragma unroll
    for (int it = 0; it < 4; ++it) {  // wave stages rows wv*32 .. wv*32+31
      const int r0 = wv * 32 + it * 8;
      const int r = r0 + lr8;
      gload16(&xb[(m0 + r) * 384 + k0 + sc8], &As[r0][0]);
      gload16(&Wq[(size_t)(n0 + r) * 384 + k0 + sc8], &Bs[r0][0]);
    }
    __syncthreads();                  // drains vmcnt(0) -> tile visible
#pragma unroll
    for (int kk = 0; kk < 2; ++kk) {
      const int cix = (((kk * 4 + g) ^ l7)) * 8;   // swizzled read chunk
      short8 af[4], bfv[4];
#pragma unroll
      for (int ms = 0; ms < 4; ++ms)
        af[ms] = *(const short8*)&As[wr + ms * 16 + lc][cix];
#pragma unroll
      for (int ns = 0; ns < 4; ++ns)
        bfv[ns] = *(const short8*)&Bs[wc + ns * 16 + lc][cix];
#pragma unroll
      for (int ms = 0; ms < 4; ++ms)
#pragma unroll
        for (int ns = 0; ns < 4; ++ns)
          acc[ms][ns] = __builtin_amdgcn_mfma_f32_16x16x32_bf16(
              af[ms], bfv[ns], acc[ms][ns], 0, 0, 0);
    }
  }

  const int sel = n0 / 384;                       // 384 = 3*128, no crossing
  const float factor = (sel == 0) ? 0.17677669529663687f : 1.0f;
  unsigned short* outp = (sel == 0) ? Qb : (sel == 1 ? Kb : Vb);
#pragma unroll
  for (int ns = 0; ns < 4; ++ns) {
    const int n = n0 + wc + ns * 16 + lc;
    const int rl = n - sel * 384;
    const int h = rl >> 5, d = rl & 31;           // 16-chunk stays in one head
    const float bias = qkv_b[n];
#pragma unroll
    for (int ms = 0; ms < 4; ++ms) {
      const size_t mrow = m0 + wr + ms * 16 + g * 4;
      const float v0 = (acc[ms][ns][0] + bias) * factor;
      const float v1 = (acc[ms][ns][1] + bias) * factor;
      const float v2 = (acc[ms][ns][2] + bias) * factor;
      const float v3 = (acc[ms][ns][3] + bias) * factor;
      const unsigned int u01 = cvtpk(v0, v1);
      const unsigned int u23 = cvtpk(v2, v3);
      unsigned short* p = &outp[(size_t)h * HS + mrow * 32 + d];
      p[0]  = (unsigned short)(u01 & 0xffffu);
      p[32] = (unsigned short)(u01 >> 16);
      p[64] = (unsigned short)(u23 & 0xffffu);
      p[96] = (unsigned short)(u23 >> 16);
    }
  }
}

// attention v5: BATCH-PAIRED — each block does two batches of the same
// (w,h): bias+mask regs shared (halves bmt traffic), 20 hoisted loads in
// flight (2x ILP), one barrier per two attention units.
// grid = 12288 = 8 xcd * (8 wl * 16 batch-pairs * 12 h)
__global__ __launch_bounds__(256) void attn5_kernel(
    unsigned short* __restrict__ Qb, const unsigned short* __restrict__ Kb,
    const unsigned short* __restrict__ Vb, const unsigned short* __restrict__ bmt) {
  __shared__ unsigned short Ps[2][NT][72];
  __shared__ unsigned short vT[2][32][72];
  const int s = blockIdx.x;
  const int xcd = s & 7, r3 = s >> 3;        // r3 in [0,1536)
  const int h = r3 % 12;
  const int t2 = r3 / 12;                    // [0,128)
  const int bp = t2 & 15;                    // batch pair
  const int w = xcd * 8 + (t2 >> 4);         // this XCD's 8 windows
  const int tid = threadIdx.x;
  const int wv = tid >> 6, ln = tid & 63, g = ln >> 4, lc = ln & 15;
  const int m0 = wv * 16;
  const int arow = (m0 + lc < NT) ? (m0 + lc) : (NT - 1);
  unsigned short* Qh = Qb + (size_t)h * HS;
  const unsigned short* Kh = Kb + (size_t)h * HS;
  const unsigned short* Vh = Vb + (size_t)h * HS;
  const size_t base0 = (size_t)((bp * 2) * 64 + w) * NT;
  const size_t base1 = base0 + (size_t)64 * NT;   // next batch, same window

  // zero vT pad cols m=54..63 for both pairs (P=0 there); 640 slots
  for (int i = tid; i < 640; i += 256) {
    const int pi = (i >= 320) ? 1 : 0;
    const int j = i - pi * 320;
    const int d = j / 10, m = NT + (j - d * 10);
    vT[pi][d][m] = 0;
  }

  // ---- hoist ALL loads for both pairs (20 independent loads) ----
  const int vr = tid >> 2, vc = (tid & 3) * 8;
  const unsigned short* bmh = &bmt[(size_t)(w * NH + h) << 12];  // [c][r]
  const int row0 = m0 + g * 4;
  uint2 uu[4];
#pragma unroll
  for (int t = 0; t < 4; ++t)
    uu[t] = *(const uint2*)&bmh[((t * 16 + lc) << 6) + row0];   // shared!

  short8 vv[2], a[2], kb[2][4];
#pragma unroll
  for (int pi = 0; pi < 2; ++pi) {
    const size_t base = pi ? base1 : base0;
    if (tid < 216)
      vv[pi] = *(const short8*)&Vh[(base + vr) * 32 + vc];
    a[pi] = *(const short8*)&Qh[(base + arow) * 32 + g * 8];
#pragma unroll
    for (int t = 0; t < 4; ++t) {
      const int col = t * 16 + lc;
      const int kr = (col < NT) ? col : (NT - 1);
      kb[pi][t] = *(const short8*)&Kh[(base + kr) * 32 + g * 8];
    }
  }

  // ---- S = q@k^T (C = bias+mask) for both pairs ----
  f32x4 sac[2][4];
#pragma unroll
  for (int pi = 0; pi < 2; ++pi)
#pragma unroll
    for (int t = 0; t < 4; ++t) {
      f32x4 c0;
      c0[0] = bf2f((unsigned short)(uu[t].x & 0xffffu));
      c0[1] = bf2f((unsigned short)(uu[t].x >> 16));
      c0[2] = bf2f((unsigned short)(uu[t].y & 0xffffu));
      c0[3] = bf2f((unsigned short)(uu[t].y >> 16));
      sac[pi][t] = __builtin_amdgcn_mfma_f32_16x16x32_bf16(
          a[pi], kb[pi][t], c0, 0, 0, 0);
    }

  // ---- row softmax for both pairs (independent chains interleave) ----
  float rmax[2][4], rsum[2][4];
#pragma unroll
  for (int pi = 0; pi < 2; ++pi)
#pragma unroll
    for (int rr = 0; rr < 4; ++rr) rmax[pi][rr] = -3.0e38f;
#pragma unroll
  for (int pi = 0; pi < 2; ++pi)
#pragma unroll
    for (int t = 0; t < 4; ++t)
#pragma unroll
      for (int rr = 0; rr < 4; ++rr)
        rmax[pi][rr] = fmaxf(rmax[pi][rr], sac[pi][t][rr]);
#pragma unroll
  for (int pi = 0; pi < 2; ++pi)
#pragma unroll
    for (int rr = 0; rr < 4; ++rr)
#pragma unroll
      for (int off = 1; off < 16; off <<= 1)
        rmax[pi][rr] = fmaxf(rmax[pi][rr], __shfl_xor(rmax[pi][rr], off));
#pragma unroll
  for (int pi = 0; pi < 2; ++pi)
#pragma unroll
    for (int rr = 0; rr < 4; ++rr) rsum[pi][rr] = 0.f;
#pragma unroll
  for (int pi = 0; pi < 2; ++pi)
#pragma unroll
    for (int t = 0; t < 4; ++t)
#pragma unroll
      for (int rr = 0; rr < 4; ++rr) {
        float p = __expf(sac[pi][t][rr] - rmax[pi][rr]);
        sac[pi][t][rr] = p;
        rsum[pi][rr] += p;
      }
#pragma unroll
  for (int pi = 0; pi < 2; ++pi)
#pragma unroll
    for (int rr = 0; rr < 4; ++rr) {
#pragma unroll
      for (int off = 1; off < 16; off <<= 1)
        rsum[pi][rr] += __shfl_xor(rsum[pi][rr], off);
      rsum[pi][rr] = 1.0f / rsum[pi][rr];
    }
#pragma unroll
  for (int pi = 0; pi < 2; ++pi)
#pragma unroll
    for (int t = 0; t < 4; ++t) {
      const int col = t * 16 + lc;
      const unsigned int u01 =
          cvtpk(sac[pi][t][0] * rsum[pi][0], sac[pi][t][1] * rsum[pi][1]);
      const unsigned int u23 =
          cvtpk(sac[pi][t][2] * rsum[pi][2], sac[pi][t][3] * rsum[pi][3]);
      if (row0 < NT)     Ps[pi][row0][col]     = (unsigned short)(u01 & 0xffffu);
      if (row0 + 1 < NT) Ps[pi][row0 + 1][col] = (unsigned short)(u01 >> 16);
      if (row0 + 2 < NT) Ps[pi][row0 + 2][col] = (unsigned short)(u23 & 0xffffu);
      if (row0 + 3 < NT) Ps[pi][row0 + 3][col] = (unsigned short)(u23 >> 16);
    }
  // ---- v transpose into LDS (both pairs) ----
  if (tid < 216) {
#pragma unroll
    for (int pi = 0; pi < 2; ++pi)
#pragma unroll
      for (int j = 0; j < 8; ++j) vT[pi][vc + j][vr] = (unsigned short)vv[pi][j];
  }
  __syncthreads();                     // one barrier for two attention units
  // ---- O = P @ V and write-back (both pairs) ----
#pragma unroll
  for (int pi = 0; pi < 2; ++pi) {
    const size_t base = pi ? base1 : base0;
    f32x4 oac[2];
    oac[0] = (f32x4){0.f, 0.f, 0.f, 0.f};
    oac[1] = (f32x4){0.f, 0.f, 0.f, 0.f};
#pragma unroll
    for (int k2 = 0; k2 < 2; ++k2) {
      short8 pa = *(const short8*)&Ps[pi][arow][k2 * 32 + g * 8];
#pragma unroll
      for (int tn = 0; tn < 2; ++tn) {
        short8 vb = *(const short8*)&vT[pi][tn * 16 + lc][k2 * 32 + g * 8];
        oac[tn] = __builtin_amdgcn_mfma_f32_16x16x32_bf16(pa, vb, oac[tn], 0, 0, 0);
      }
    }
#pragma unroll
    for (int tn = 0; tn < 2; ++tn) {
      const int d = tn * 16 + lc;
      const unsigned int u01 = cvtpk(oac[tn][0], oac[tn][1]);
      const unsigned int u23 = cvtpk(oac[tn][2], oac[tn][3]);
      unsigned short* p = &Qh[(base + row0) * 32 + d];
      if (row0 < NT)     p[0]  = (unsigned short)(u01 & 0xffffu);
      if (row0 + 1 < NT) p[32] = (unsigned short)(u01 >> 16);
      if (row0 + 2 < NT) p[64] = (unsigned short)(u23 & 0xffffu);
      if (row0 + 3 < NT) p[96] = (unsigned short)(u23 >> 16);
    }
  }
}

// proj GEMM over h-major A (the O planes) — R6-proven reg-staged 2-barrier.
// out[m][n]=sum_k A[m][k]*Wp[n][k]+b;  A[m][h*32+d] = AO[h*HS + m*32 + d]
// grid = 2592 = 8 xcd * 108 m * 3 n
__global__ __launch_bounds__(256) void proj_hmajor(
    const unsigned short* __restrict__ AO, const unsigned short* __restrict__ Wp,
    const float* __restrict__ proj_b, float* __restrict__ out) {
  __shared__ unsigned short As[128][72];
  __shared__ unsigned short Bs[128][72];
  const int s = blockIdx.x;
  const int xcd = s & 7, slot = s >> 3;
  const size_t m0 = (size_t)(xcd * 108 + slot / 3) * 128;
  const int n0 = (slot % 3) * 128;
  const int tid = threadIdx.x;
  const int wv = tid >> 6, ln = tid & 63, g = ln >> 4, lc = ln & 15;
  const int wr = (wv >> 1) * 64, wc = (wv & 1) * 64;
  f32x4 acc[4][4];
#pragma unroll
  for (int i = 0; i < 4; ++i)
#pragma unroll
    for (int j = 0; j < 4; ++j) acc[i][j] = (f32x4){0.f, 0.f, 0.f, 0.f};

  const int srow = tid >> 3, l8 = tid & 7;
  for (int kc = 0; kc < 6; ++kc) {
    const int k0 = kc * 64;
    const int kg = k0 + l8 * 8;
    const int hh = kg >> 5, dd = kg & 31;         // 8-chunk stays in one head
#pragma unroll
    for (int it = 0; it < 4; ++it) {
      const int r = srow + it * 32;
      *(short8*)&As[r][l8 * 8] =
          *(const short8*)&AO[(size_t)hh * HS + (m0 + r) * 32 + dd];
      *(short8*)&Bs[r][l8 * 8] =
          *(const short8*)&Wp[(size_t)(n0 + r) * 384 + kg];
    }
    __syncthreads();
#pragma unroll
    for (int kk = 0; kk < 2; ++kk) {
      short8 af[4], bfv[4];
#pragma unroll
      for (int ms = 0; ms < 4; ++ms)
        af[ms] = *(const short8*)&As[wr + ms * 16 + lc][kk * 32 + g * 8];
#pragma unroll
      for (int ns = 0; ns < 4; ++ns)
        bfv[ns] = *(const short8*)&Bs[wc + ns * 16 + lc][kk * 32 + g * 8];
#pragma unroll
      for (int ms = 0; ms < 4; ++ms)
#pragma unroll
        for (int ns = 0; ns < 4; ++ns)
          acc[ms][ns] = __builtin_amdgcn_mfma_f32_16x16x32_bf16(
              af[ms], bfv[ns], acc[ms][ns], 0, 0, 0);
    }
    __syncthreads();
  }
#pragma unroll
  for (int ns = 0; ns < 4; ++ns) {
    const int n = n0 + wc + ns * 16 + lc;
    const float pb = proj_b[n];
#pragma unroll
    for (int ms = 0; ms < 4; ++ms)
#pragma unroll
      for (int rr = 0; rr < 4; ++rr) {
        const size_t m = m0 + wr + ms * 16 + g * 4 + rr;
        out[m * 384 + n] = acc[ms][ns][rr] + pb;
      }
  }
}

// ================================================= FALLBACK (round-1) =====
__global__ __launch_bounds__(256) void prep_kernel(
    const float* __restrict__ qkv_w, const float* __restrict__ proj_w,
    const float* __restrict__ mask, const float* __restrict__ rpb,
    const int* __restrict__ rel,
    unsigned short* __restrict__ Wq, unsigned short* __restrict__ Wp,
    float* __restrict__ bias_tab, float* __restrict__ maskp) {
  int idx = blockIdx.x * 256 + threadIdx.x;
  if (idx < 1152 * 384) { Wq[idx] = f2bf(qkv_w[idx]); return; }
  idx -= 1152 * 384;
  if (idx < 384 * 384) { Wp[idx] = f2bf(proj_w[idx]); return; }
  idx -= 384 * 384;
  if (idx < NH * 64 * 64) {
    int h = idx >> 12, r = (idx >> 6) & 63, c = idx & 63;
    float v;
    if (r >= NT || c >= NT) v = -1e30f;
    else if (r >= 5 && c >= 5) v = rpb[rel[(r - 5) * 49 + (c - 5)] * NH + h];
    else v = 0.0f;
    bias_tab[idx] = v;
    return;
  }
  idx -= NH * 64 * 64;
  if (idx < NWIN * 64 * 64) {
    int w = idx >> 12, r = (idx >> 6) & 63, c = idx & 63;
    float v = 0.0f;
    if (r >= 5 && r < NT && c >= 5 && c < NT)
      v = mask[w * 2401 + (r - 5) * 49 + (c - 5)];
    maskp[idx] = v;
  }
}

__global__ __launch_bounds__(256) void fused_attn(
    const float* __restrict__ x, const unsigned short* __restrict__ Wq,
    const float* __restrict__ qkv_b, const float* __restrict__ bias_tab,
    const float* __restrict__ maskp, unsigned short* __restrict__ AO) {
  __shared__ unsigned short xs[NT][392];
  __shared__ unsigned short qs[NT][40];
  __shared__ unsigned short ksm[NT][40];
  __shared__ unsigned short vT[32][72];
  __shared__ unsigned short Ps[NT][72];
  const int b = blockIdx.x;
  const int tid = threadIdx.x;
  const int wv = tid >> 6, ln = tid & 63;
  const int g = ln >> 4, lc = ln & 15;
  const int m0 = wv * 16;
  const int wi = b & 63;
  const float scale = 0.17677669529663687f;
  const float* xb = x + (size_t)b * (NT * DIM);
  for (int i = tid; i < NT * DIM / 4; i += 256) {
    float4 v = ((const float4*)xb)[i];
    int e = i * 4, r = e / DIM, c = e - r * DIM;
    unsigned short* p = &xs[r][c];
    p[0] = f2bf(v.x); p[1] = f2bf(v.y); p[2] = f2bf(v.z); p[3] = f2bf(v.w);
  }
  __syncthreads();
  const int arow = (m0 + lc < NT) ? (m0 + lc) : (NT - 1);
  for (int h = 0; h < NH; ++h) {
    f32x4 acc[6];
#pragma unroll
    for (int t = 0; t < 6; ++t) acc[t] = (f32x4){0.f, 0.f, 0.f, 0.f};
#pragma unroll 2
    for (int kk = 0; kk < 12; ++kk) {
      short8 a = *(const short8*)&xs[arow][kk * 32 + g * 8];
#pragma unroll
      for (int t = 0; t < 6; ++t) {
        const int sel = t >> 1;
        const int wrow = sel * 384 + h * 32 + (t & 1) * 16 + lc;
        short8 bfr = *(const short8*)&Wq[wrow * 384 + kk * 32 + g * 8];
        acc[t] = __builtin_amdgcn_mfma_f32_16x16x32_bf16(a, bfr, acc[t], 0, 0, 0);
      }
    }
#pragma unroll
    for (int t = 0; t < 6; ++t) {
      const int sel = t >> 1;
      const int d = (t & 1) * 16 + lc;
      const float bias = qkv_b[sel * 384 + h * 32 + d];
#pragma unroll
      for (int r = 0; r < 4; ++r) {
        const int m = m0 + g * 4 + r;
        float v = acc[t][r] + bias;
        if (sel == 2) vT[d][m] = f2bf(v);
        else if (m < NT) {
          if (sel == 0) qs[m][d] = f2bf(v * scale);
          else ksm[m][d] = f2bf(v);
        }
      }
    }
    __syncthreads();
    f32x4 sac[4];
    {
      short8 a = *(const short8*)&qs[arow][g * 8];
#pragma unroll
      for (int t = 0; t < 4; ++t) {
        const int kr = (t * 16 + lc < NT) ? (t * 16 + lc) : (NT - 1);
        short8 bfr = *(const short8*)&ksm[kr][g * 8];
        sac[t] = __builtin_amdgcn_mfma_f32_16x16x32_bf16(
            a, bfr, (f32x4){0.f, 0.f, 0.f, 0.f}, 0, 0, 0);
      }
    }
    const float* bt = bias_tab + h * 4096;
    const float* mp = maskp + wi * 4096;
    float sv[4][4];
    float rmax[4];
#pragma unroll
    for (int r = 0; r < 4; ++r) rmax[r] = -3.0e38f;
#pragma unroll
    for (int t = 0; t < 4; ++t) {
      const int col = t * 16 + lc;
#pragma unroll
      for (int r = 0; r < 4; ++r) {
        const int row = m0 + g * 4 + r;
        float s2 = sac[t][r] + bt[row * 64 + col] + mp[row * 64 + col];
        sv[t][r] = s2;
        rmax[r] = fmaxf(rmax[r], s2);
      }
    }
#pragma unroll
    for (int r = 0; r < 4; ++r)
#pragma unroll
      for (int off = 1; off < 16; off <<= 1)
        rmax[r] = fmaxf(rmax[r], __shfl_xor(rmax[r], off));
    float rsum[4] = {0.f, 0.f, 0.f, 0.f};
#pragma unroll
    for (int t = 0; t < 4; ++t)
#pragma unroll
      for (int r = 0; r < 4; ++r) {
        float p = __expf(sv[t][r] - rmax[r]);
        sv[t][r] = p;
        rsum[r] += p;
      }
#pragma unroll
    for (int r = 0; r < 4; ++r) {
#pragma unroll
      for (int off = 1; off < 16; off <<= 1)
        rsum[r] += __shfl_xor(rsum[r], off);
      rsum[r] = 1.0f / rsum[r];
    }
#pragma unroll
    for (int t = 0; t < 4; ++t) {
      const int col = t * 16 + lc;
#pragma unroll
      for (int r = 0; r < 4; ++r) {
        const int row = m0 + g * 4 + r;
        if (row < NT) Ps[row][col] = f2bf(sv[t][r] * rsum[r]);
      }
    }
    __syncthreads();
    f32x4 oac[2];
    oac[0] = (f32x4){0.f, 0.f, 0.f, 0.f};
    oac[1] = (f32x4){0.f, 0.f, 0.f, 0.f};
#pragma unroll
    for (int k2 = 0; k2 < 2; ++k2) {
      short8 a = *(const short8*)&Ps[arow][k2 * 32 + g * 8];
#pragma unroll
      for (int tn = 0; tn < 2; ++tn) {
        short8 bfr = *(const short8*)&vT[tn * 16 + lc][k2 * 32 + g * 8];
        oac[tn] = __builtin_amdgcn_mfma_f32_16x16x32_bf16(a, bfr, oac[tn], 0, 0, 0);
      }
    }
    unsigned short* aob = AO + (size_t)b * (NT * DIM) + h * 32;
#pragma unroll
    for (int tn = 0; tn < 2; ++tn) {
      const int d = tn * 16 + lc;
#pragma unroll
      for (int r = 0; r < 4; ++r) {
        const int m = m0 + g * 4 + r;
        if (m < NT) aob[m * DIM + d] = f2bf(oac[tn][r]);
      }
    }
    __syncthreads();
  }
}

__global__ __launch_bounds__(256) void proj_kernel(
    const unsigned short* __restrict__ AO, const unsigned short* __restrict__ Wp,
    const float* __restrict__ proj_b, float* __restrict__ out, int lda) {
  __shared__ unsigned short As[128][72];
  __shared__ unsigned short Bs[128][72];
  const int s = blockIdx.x;
  const int xcd = s & 7, slot = s >> 3;
  const size_t m0 = (size_t)(xcd * 108 + slot / 3) * 128;
  const int n0 = (slot % 3) * 128;
  const int tid = threadIdx.x;
  const int wv = tid >> 6, ln = tid & 63, g = ln >> 4, lc = ln & 15;
  const int wr = (wv >> 1) * 64, wc = (wv & 1) * 64;
  f32x4 acc[4][4];
#pragma unroll
  for (int i = 0; i < 4; ++i)
#pragma unroll
    for (int j = 0; j < 4; ++j) acc[i][j] = (f32x4){0.f, 0.f, 0.f, 0.f};

  const int srow = tid >> 3, l8 = tid & 7;
  for (int kc = 0; kc < 6; ++kc) {
    const int k0 = kc * 64;
#pragma unroll
    for (int it = 0; it < 4; ++it) {
      const int r = srow + it * 32;
      *(short8*)&As[r][l8 * 8] =
          *(const short8*)&AO[(m0 + r) * (size_t)lda + k0 + l8 * 8];
      *(short8*)&Bs[r][l8 * 8] =
          *(const short8*)&Wp[(size_t)(n0 + r) * 384 + k0 + l8 * 8];
    }
    __syncthreads();
#pragma unroll
    for (int kk = 0; kk < 2; ++kk) {
      short8 af[4], bfr[4];
#pragma unroll
      for (int ms = 0; ms < 4; ++ms)
        af[ms] = *(const short8*)&As[wr + ms * 16 + lc][kk * 32 + g * 8];
#pragma unroll
      for (int ns = 0; ns < 4; ++ns)
        bfr[ns] = *(const short8*)&Bs[wc + ns * 16 + lc][kk * 32 + g * 8];
#pragma unroll
      for (int ms = 0; ms < 4; ++ms)
#pragma unroll
        for (int ns = 0; ns < 4; ++ns)
          acc[ms][ns] = __builtin_amdgcn_mfma_f32_16x16x32_bf16(
              af[ms], bfr[ns], acc[ms][ns], 0, 0, 0);
    }
    __syncthreads();
  }
#pragma unroll
  for (int ns = 0; ns < 4; ++ns) {
    const int n = n0 + wc + ns * 16 + lc;
    const float pb = proj_b[n];
#pragma unroll
    for (int ms = 0; ms < 4; ++ms)
#pragma unroll
      for (int rr = 0; rr < 4; ++rr) {
        const size_t m = m0 + wr + ms * 16 + g * 4 + rr;
        out[m * 384 + n] = acc[ms][ns][rr] + pb;
      }
  }
}

// -------------------------------------------------------------- launch ----
extern "C" void kernel_launch(void* const* d_in, const int* in_sizes, int n_in,
                              void* d_out, int out_size, void* d_ws, size_t ws_size,
                              hipStream_t stream) {
  const float* x      = (const float*)d_in[0];
  const float* mask   = (const float*)d_in[1];
  const float* qkv_w  = (const float*)d_in[2];
  const float* qkv_b  = (const float*)d_in[3];
  const float* proj_w = (const float*)d_in[4];
  const float* proj_b = (const float*)d_in[5];
  const float* rpb    = (const float*)d_in[6];
  const int*   rel    = (const int*)d_in[7];
  float* out = (float*)d_out;

  const size_t QKV_ELEMS = (size_t)3 * NH * HS;  // 127,401,984
  const size_t WQ_ELEMS = 1152 * 384, WP_ELEMS = 384 * 384;
  const size_t BMT_ELEMS = (size_t)NWIN * NH * 4096;
  const size_t need = (QKV_ELEMS + WQ_ELEMS + WP_ELEMS + BMT_ELEMS) * 2;

  if (ws_size >= need) {
    // -------- fast path: h-major Q/K/V planes --------
    unsigned short* Qb  = (unsigned short*)d_ws;
    unsigned short* Kb  = Qb + NH * HS;
    unsigned short* Vb  = Kb + NH * HS;
    unsigned short* Wq  = Vb + NH * HS;
    unsigned short* Wp  = Wq + WQ_ELEMS;
    unsigned short* bmt = Wp + WP_ELEMS;
    // xb (bf16 copy of x) lives in d_out (85 MB of 170 MB); dead before proj
    unsigned short* xb = (unsigned short*)d_out;

    convert_x<<<20736, 256, 0, stream>>>(x, xb);
    prep2_kernel<<<14592, 256, 0, stream>>>(qkv_w, proj_w, mask, rpb, rel,
                                            Wq, Wp, bmt);
    qkv_gemm5<<<7776, 256, 0, stream>>>(xb, Wq, qkv_b, Qb, Kb, Vb);
    attn5_kernel<<<12288, 256, 0, stream>>>(Qb, Kb, Vb, bmt);
    proj_hmajor<<<2592, 256, 0, stream>>>(Qb, Wp, proj_b, out);
  } else {
    // -------- fallback: round-1 fused path (88 MB scratch) --------
    unsigned short* Wq = (unsigned short*)d_ws;
    unsigned short* Wp = Wq + 442368;
    float* bias_tab = (float*)(Wp + 147456);
    float* maskp = bias_tab + 12 * 64 * 64;
    unsigned short* AO = (unsigned short*)(maskp + 64 * 64 * 64);
    prep_kernel<<<3520, 256, 0, stream>>>(qkv_w, proj_w, mask, rpb, rel,
                                          Wq, Wp, bias_tab, maskp);
    fused_attn<<<2048, 256, 0, stream>>>(x, Wq, qkv_b, bias_tab, maskp, AO);
    proj_kernel<<<2592, 256, 0, stream>>>(AO, Wp, proj_b, out, 384);
  }
}